// Round 9
// baseline (200.004 us; speedup 1.0000x reference)
//
#include <hip/hip_runtime.h>
#include <hip/hip_bf16.h>

typedef unsigned int uint;

#define T_STEPS 32

// ---- workspace dword offsets ----
#define OFF_WB    0        // 30720: GRU B-frags
#define OFF_PJB   30720    // 4096 : proj B-frags
#define OFF_D0B   34816    // 6144 : drift_w0 B-frags (8 slots x 3 kt)
#define OFF_D1B   40960    // 8192
#define OFF_D2B   49152    // 8192
#define OFF_G0B   57344    // 6144
#define OFF_G1B   63488    // 8192
#define OFF_W3P   71680    // 960 : drift_w3 plain [o][64 uints]
#define OFF_G2P   72640    // 960 : diff_w2  plain
#define OFF_CTXG  73600    // 65536: ctx f16 [4096][64]

typedef _Float16 h2v  __attribute__((ext_vector_type(2)));
typedef _Float16 half8 __attribute__((ext_vector_type(8)));
typedef float    f32x4 __attribute__((ext_vector_type(4)));

union FB { uint4 u4; half8 h; };

__device__ inline uint pack2f(float a, float b) {
  _Float16 ha = (_Float16)a, hb = (_Float16)b;
  unsigned short ua, ub;
  __builtin_memcpy(&ua, &ha, 2);
  __builtin_memcpy(&ub, &hb, 2);
  return (uint)ua | ((uint)ub << 16);
}

__device__ inline float dot2(uint w, uint a, float acc) {
#if __has_builtin(__builtin_amdgcn_fdot2)
  union U { uint u; h2v h; };
  U uw, ua; uw.u = w; ua.u = a;
  return __builtin_amdgcn_fdot2(uw.h, ua.h, acc, false);
#else
  union U { uint u; _Float16 h[2]; };
  U uw, ua; uw.u = w; ua.u = a;
  return acc + (float)uw.h[0] * (float)ua.h[0] + (float)uw.h[1] * (float)ua.h[1];
#endif
}

#define DOT4(accv, wv, xv)                                             \
  accv = dot2((wv).x, (xv).x, accv); accv = dot2((wv).y, (xv).y, accv);\
  accv = dot2((wv).z, (xv).z, accv); accv = dot2((wv).w, (xv).w, accv);

__device__ inline float sigm(float x) { return 1.f / (1.f + __expf(-x)); }
__device__ inline float tanh_f(float x) {
  float ax = fabsf(x);
  float e = __expf(2.f * ax);
  float t = 1.f - 2.f / (e + 1.f);
  return copysignf(t, x);
}
__device__ inline float silu_f(float x) { return x / (1.f + __expf(-x)); }

__device__ inline float map89(const float* __restrict__ W, int u, int k) {
  if (k < 25) return W[u * 89 + k];
  if (k < 32) return 0.f;
  return W[u * 89 + k - 7];
}

// ======================= weight pre-pack =======================
__global__ __launch_bounds__(256) void prep_kernel(
    const float* __restrict__ wih, const float* __restrict__ whh,
    const float* __restrict__ pw,
    const float* __restrict__ dw0, const float* __restrict__ dw1,
    const float* __restrict__ dw2, const float* __restrict__ gw0,
    const float* __restrict__ gw1, const float* __restrict__ dw3,
    const float* __restrict__ gw2, uint* __restrict__ wsu) {
  int id = blockIdx.x * 256 + threadIdx.x;
  if (id < 30720) {
    int i = id & 3, l = (id >> 2) & 63, t3 = id >> 8;
    int kt = t3 % 5, wg = t3 / 5;
    int w = wg / 3, gi = wg % 3;
    int row = gi * 128 + w * 16 + (l & 15);
    int k = ((l >> 4) << 3) + i * 2;
    float a, b;
    if (kt == 0) {
      a = (k     < 25) ? wih[row * 25 + k]     : 0.f;
      b = (k + 1 < 25) ? wih[row * 25 + k + 1] : 0.f;
    } else {
      int kh = (kt - 1) * 32 + k;
      a = whh[row * 128 + kh];
      b = whh[row * 128 + kh + 1];
    }
    wsu[OFF_WB + id] = pack2f(a, b);
  } else if (id < 34816) {               // proj B-frags
    int t = id - 30720;
    int i = t & 3, l = (t >> 2) & 63, wkt = t >> 8;
    int kt = wkt & 3, w = wkt >> 2;
    int u = w * 16 + (l & 15);
    int k = kt * 32 + ((l >> 4) << 3) + i * 2;
    wsu[OFF_PJB + t] = pack2f(pw[u * 128 + k], pw[u * 128 + k + 1]);
  } else if (id < 40960) {               // drift_w0
    int t = id - 34816;
    int i = t & 3, l = (t >> 2) & 63, wkt = t >> 8;
    int kt = wkt % 3, w = wkt / 3;
    int u = w * 16 + (l & 15);
    int k = kt * 32 + ((l >> 4) << 3) + i * 2;
    wsu[OFF_D0B + t] = pack2f(map89(dw0, u, k), map89(dw0, u, k + 1));
  } else if (id < 49152) {               // drift_w1
    int t = id - 40960;
    int i = t & 3, l = (t >> 2) & 63, wkt = t >> 8;
    int kt = wkt & 3, w = wkt >> 2;
    int u = w * 16 + (l & 15);
    int k = kt * 32 + ((l >> 4) << 3) + i * 2;
    wsu[OFF_D1B + t] = pack2f(dw1[u * 128 + k], dw1[u * 128 + k + 1]);
  } else if (id < 57344) {               // drift_w2
    int t = id - 49152;
    int i = t & 3, l = (t >> 2) & 63, wkt = t >> 8;
    int kt = wkt & 3, w = wkt >> 2;
    int u = w * 16 + (l & 15);
    int k = kt * 32 + ((l >> 4) << 3) + i * 2;
    wsu[OFF_D2B + t] = pack2f(dw2[u * 128 + k], dw2[u * 128 + k + 1]);
  } else if (id < 63488) {               // diff_w0
    int t = id - 57344;
    int i = t & 3, l = (t >> 2) & 63, wkt = t >> 8;
    int kt = wkt % 3, w = wkt / 3;
    int u = w * 16 + (l & 15);
    int k = kt * 32 + ((l >> 4) << 3) + i * 2;
    wsu[OFF_G0B + t] = pack2f(map89(gw0, u, k), map89(gw0, u, k + 1));
  } else if (id < 71680) {               // diff_w1
    int t = id - 63488;
    int i = t & 3, l = (t >> 2) & 63, wkt = t >> 8;
    int kt = wkt & 3, w = wkt >> 2;
    int u = w * 16 + (l & 15);
    int k = kt * 32 + ((l >> 4) << 3) + i * 2;
    wsu[OFF_G1B + t] = pack2f(gw1[u * 128 + k], gw1[u * 128 + k + 1]);
  } else if (id < 72640) {               // drift_w3 plain [o][64]
    int t = id - 71680;
    int o = t >> 6, k2 = t & 63;
    wsu[OFF_W3P + t] = pack2f(dw3[o * 128 + 2 * k2], dw3[o * 128 + 2 * k2 + 1]);
  } else if (id < 73600) {               // diff_w2 plain
    int t = id - 72640;
    int o = t >> 6, k2 = t & 63;
    wsu[OFF_G2P + t] = pack2f(gw2[o * 128 + 2 * k2], gw2[o * 128 + 2 * k2 + 1]);
  }
}

// ======================= GRU encoder =======================
// grid 256 x 512; block owns 16 batch rows. Writes ctx (f16) to global.
__global__ __launch_bounds__(512) void gru_kernel(
    const float* __restrict__ ctp, const uint* __restrict__ wsu,
    const float* __restrict__ gbias, const float* __restrict__ gbn,
    const float* __restrict__ projb, _Float16* __restrict__ ctxg) {
  __shared__ __align__(16) _Float16 x2[T_STEPS][4][16][8];  // 32KB
  __shared__ __align__(16) _Float16 hf[2][4][4][16][8];     // 8KB
  const int tid = threadIdx.x;
  const int rb = blockIdx.x * 16;
  uint* x2u = (uint*)x2;

  for (int idx = tid; idx < T_STEPS * 16 * 16; idx += 512) {
    int k2 = idx & 15, r = (idx >> 4) & 15, t = idx >> 8;
    const float* base = ctp + ((rb + r) * T_STEPS + t) * 25;
    int k0 = 2 * k2;
    float v0 = 0.f, v1 = 0.f;
    if (k0 < 25)     { int i5 = k0 / 5,     j5 = k0 % 5;     v0 = 0.5f * (base[i5*5+j5] + base[j5*5+i5]); }
    if (k0 + 1 < 25) { int i5 = (k0+1) / 5, j5 = (k0+1) % 5; v1 = 0.5f * (base[i5*5+j5] + base[j5*5+i5]); }
    int q = k2 >> 2, jh = k2 & 3;
    x2u[((t * 4 + q) * 16 + r) * 4 + jh] = pack2f(v0, v1);
  }

  const int w = tid >> 6, l = tid & 63;
  const int lm = l & 15, lq = l >> 4;
  const int u = w * 16 + lm;
  const int ku = u >> 5, qu = (u >> 3) & 3, ju = u & 7;
  FB Bf[3][5];
  const uint4* wb4p = (const uint4*)(wsu + OFF_WB);
#pragma unroll
  for (int gi = 0; gi < 3; gi++)
#pragma unroll
    for (int kt = 0; kt < 5; kt++)
      Bf[gi][kt].u4 = wb4p[((w * 3 + gi) * 5 + kt) * 64 + l];
  const float br = gbias[u], bz = gbias[128 + u], bg = gbias[256 + u], bn = gbn[u];
  float hprev[4] = {0.f, 0.f, 0.f, 0.f};
  __syncthreads();

  f32x4 z4 = {0.f, 0.f, 0.f, 0.f};
  half8 axn = *(const half8*)(&x2[0][lq][lm][0]);
  f32x4 pxr = __builtin_amdgcn_mfma_f32_16x16x32_f16(axn, Bf[0][0].h, z4, 0, 0, 0);
  f32x4 pxz = __builtin_amdgcn_mfma_f32_16x16x32_f16(axn, Bf[1][0].h, z4, 0, 0, 0);
  f32x4 pxg = __builtin_amdgcn_mfma_f32_16x16x32_f16(axn, Bf[2][0].h, z4, 0, 0, 0);
  for (int t = 0; t < T_STEPS; t++) {
    f32x4 cr = pxr, cz = pxz, cgv = pxg;
    f32x4 ch = {0.f, 0.f, 0.f, 0.f};
    if (t > 0) {
      const int p = t & 1;
#pragma unroll
      for (int kk = 0; kk < 4; kk++) {
        half8 ah = *(const half8*)(&hf[p][kk][lq][lm][0]);
        cr = __builtin_amdgcn_mfma_f32_16x16x32_f16(ah, Bf[0][1 + kk].h, cr, 0, 0, 0);
        cz = __builtin_amdgcn_mfma_f32_16x16x32_f16(ah, Bf[1][1 + kk].h, cz, 0, 0, 0);
        ch = __builtin_amdgcn_mfma_f32_16x16x32_f16(ah, Bf[2][1 + kk].h, ch, 0, 0, 0);
      }
    }
    if (t < T_STEPS - 1) {
      axn = *(const half8*)(&x2[t + 1][lq][lm][0]);
      pxr = __builtin_amdgcn_mfma_f32_16x16x32_f16(axn, Bf[0][0].h, z4, 0, 0, 0);
      pxz = __builtin_amdgcn_mfma_f32_16x16x32_f16(axn, Bf[1][0].h, z4, 0, 0, 0);
      pxg = __builtin_amdgcn_mfma_f32_16x16x32_f16(axn, Bf[2][0].h, z4, 0, 0, 0);
    }
    const int wp = (t + 1) & 1;
#pragma unroll
    for (int s = 0; s < 4; s++) {
      float r = sigm(cr[s] + br);
      float z = sigm(cz[s] + bz);
      float g = tanh_f(cgv[s] + bg + r * (ch[s] + bn));
      float hn = (1.f - z) * g + z * hprev[s];
      hprev[s] = hn;
      hf[wp][ku][qu][lq * 4 + s][ju] = (_Float16)hn;
    }
    __syncthreads();
  }

  // proj via MFMA (waves 0-3) -> global f16 ctx
  if (w < 4) {
    FB Pf[4];
#pragma unroll
    for (int kt = 0; kt < 4; kt++)
      Pf[kt].u4 = ((const uint4*)(wsu + OFF_PJB))[(w * 4 + kt) * 64 + l];
    f32x4 c = {0.f, 0.f, 0.f, 0.f};
#pragma unroll
    for (int kt = 0; kt < 4; kt++) {
      half8 a = *(const half8*)(&hf[0][kt][lq][lm][0]);
      c = __builtin_amdgcn_mfma_f32_16x16x32_f16(a, Pf[kt].h, c, 0, 0, 0);
    }
    const float pbv = projb[u];
#pragma unroll
    for (int s = 0; s < 4; s++)
      ctxg[(rb + lq * 4 + s) * 64 + u] = (_Float16)(c[s] + pbv);
  }
}

// ======================= SDE kernel =======================
template <int KT>
__device__ inline void mlp_pair(const _Float16* __restrict__ aA,
                                const FB* B0, const FB* B1,
                                float bias0, float bias1,
                                _Float16* __restrict__ outA,
                                int lm, int lq, int ubase) {
  f32x4 c0 = {0.f, 0.f, 0.f, 0.f}, c1 = {0.f, 0.f, 0.f, 0.f};
#pragma unroll
  for (int kt = 0; kt < KT; kt++) {
    half8 a = *(const half8*)(aA + ((kt * 4 + lq) * 16 + lm) * 8);
    c0 = __builtin_amdgcn_mfma_f32_16x16x32_f16(a, B0[kt].h, c0, 0, 0, 0);
    c1 = __builtin_amdgcn_mfma_f32_16x16x32_f16(a, B1[kt].h, c1, 0, 0, 0);
  }
  int u0 = ubase + lm, u1 = ubase + 16 + lm;
  int base0 = (u0 >> 3) * 128 + (u0 & 7);
  int base1 = (u1 >> 3) * 128 + (u1 & 7);
#pragma unroll
  for (int s = 0; s < 4; s++) {
    outA[base0 + (lq * 4 + s) * 8] = (_Float16)silu_f(c0[s] + bias0);
    outA[base1 + (lq * 4 + s) * 8] = (_Float16)silu_f(c1[s] + bias1);
  }
}

__device__ inline float bpf(int addr, float v) {
  return __int_as_float(__builtin_amdgcn_ds_bpermute(addr, __float_as_int(v)));
}
__device__ inline float mm5b(int iA, int iB, float A, float B) {
  float c = 0.f;
#pragma unroll
  for (int k = 0; k < 5; k++)
    c = fmaf(bpf(iA + 4 * k, A), bpf(iB + 20 * k, B), c);
  return c;
}

#define NS_ITER do { \
  float P_  = mm5b(iA0, iB0, Zv, Yv); \
  float Tm_ = 1.5f * gdel - 0.5f * P_; \
  float Yn_ = mm5b(iA0, iB0, Yv, Tm_); \
  float Zn_ = mm5b(iA0, iB0, Tm_, Zv); \
  Yv = Yn_; Zv = Zn_; } while (0)

// grid 512 x 256; block owns 8 batch elements; 2 blocks/CU.
__global__ __launch_bounds__(256, 2) void sde_kernel(
    const float* __restrict__ ctp, const float* __restrict__ dWp,
    const uint* __restrict__ wsu,
    const float* __restrict__ db0, const float* __restrict__ db1,
    const float* __restrict__ db2, const float* __restrict__ b3,
    const float* __restrict__ gb0, const float* __restrict__ gb1,
    const float* __restrict__ gb2, float* __restrict__ outp) {
  __shared__ __align__(16) _Float16 abuf[1536 + 4 * 2048];  // inpA + bufA..D, 19KB
  __shared__ __align__(16) uint w3s[15 * 68 + 4];
  __shared__ __align__(16) uint gw2s[15 * 68 + 4];
  __shared__ float sig_s[8 * 28];
  __shared__ float coeff_s[128];
  __shared__ float coeff2_s[128];
  const int tid = threadIdx.x;
  const int eb = blockIdx.x * 8;
  _Float16* inpA = abuf;
  _Float16* bufA = abuf + 1536;
  _Float16* bufB = abuf + 3584;
  _Float16* bufC = abuf + 5632;
  _Float16* bufD = abuf + 7680;
  const int w = tid >> 6, l = tid & 63;
  const int lm = l & 15, lq = l >> 4;
  const int role = w >> 1, wq = w & 1;   // role 0: drift (w0-1), 1: diff (w2-3)

  for (int i = tid; i < 960; i += 256) {
    int o = i >> 6, k2 = i & 63;
    w3s[o * 68 + k2]  = wsu[OFF_W3P + i];
    gw2s[o * 68 + k2] = wsu[OFF_G2P + i];
  }
  const _Float16* ctxh = (const _Float16*)(wsu + OFF_CTXG);
  for (int idx = tid; idx < 512; idx += 256) {
    int e = idx >> 6, c = idx & 63, k = 32 + c;
    inpA[(k >> 3) * 128 + e * 8 + (k & 7)] = ctxh[(eb + e) * 64 + c];
  }
  for (int idx = tid; idx < 768; idx += 256) {   // zero rows 8-15
    int c16 = idx >> 6, rem = idx & 63;
    inpA[c16 * 128 + (8 + (rem >> 3)) * 8 + (rem & 7)] = (_Float16)0.f;
  }
  for (int idx = tid; idx < 200; idx += 256) {
    int e = idx / 25, k = idx % 25;
    int i5 = k / 5, j5 = k % 5;
    const float* base = ctp + ((eb + e) * T_STEPS + 31) * 25;
    float v = 0.5f * (base[i5 * 5 + j5] + base[j5 * 5 + i5]);
    sig_s[e * 28 + k] = v;
    inpA[(k >> 3) * 128 + e * 8 + (k & 7)] = (_Float16)v;
  }
  if (tid < 56) {
    int e = tid / 7, p = 25 + tid % 7;
    inpA[(p >> 3) * 128 + e * 8 + (p & 7)] = (_Float16)0.f;
  }

  FB F0[4][3], F1[4][4], F2[4][4];
  {
    const uint4* p0 = (const uint4*)(wsu + (role ? OFF_G0B : OFF_D0B));
    const uint4* p1 = (const uint4*)(wsu + (role ? OFF_G1B : OFF_D1B));
    const uint4* p2 = (const uint4*)(wsu + (role ? OFF_G1B : OFF_D2B)); // diff: dummy
#pragma unroll
    for (int s = 0; s < 4; s++) {
      int slot = wq * 4 + s;
#pragma unroll
      for (int kt = 0; kt < 3; kt++) F0[s][kt].u4 = p0[(slot * 3 + kt) * 64 + l];
#pragma unroll
      for (int kt = 0; kt < 4; kt++) {
        F1[s][kt].u4 = p1[(slot * 4 + kt) * 64 + l];
        F2[s][kt].u4 = p2[(slot * 4 + kt) * 64 + l];
      }
    }
  }
  float b0s[4], b1s[4], b2s[4];
#pragma unroll
  for (int s = 0; s < 4; s++) {
    int us = wq * 64 + s * 16 + lm;
    b0s[s] = role ? gb0[us] : db0[us];
    b1s[s] = role ? gb1[us] : db1[us];
    b2s[s] = role ? 0.f : db2[us];
  }

  const int ge = tid >> 5, glane = tid & 31;
  const int gli = (glane < 25) ? glane : 0;
  const int gii = gli / 5, gjj = gli % 5;
  const float gdel = (gii == gjj) ? 1.f : 0.f;
  const int gbase = (l & 32) << 2;
  const int iA0 = gbase + gii * 20;
  const int iB0 = gbase + gjj * 4;
  const int iT0 = gbase + (gjj * 5 + gii) * 4;
  const float b3r = (glane < 15) ? b3[glane] : 0.f;
  const float g2r = (glane < 15) ? gb2[glane] : 0.f;
  __syncthreads();

  for (int st = 0; st < 5; st++) {
    float S = sig_s[ge * 28 + gli];
    float tr = 0.f;
#pragma unroll
    for (int d = 0; d < 5; d++) tr += bpf(gbase + 24 * d, S);
    const float That = S * (2.298851f / tr) - 1.068966f * gdel;
    float dwv = (glane < 15) ? dWp[((eb + ge) * 5 + st) * 15 + glane] : 0.f;
    float Yv, Zv;
    // p1: layer0 (both roles) + cheb4 preconditioner
    mlp_pair<3>(inpA, F0[0], F0[1], b0s[0], b0s[1], role ? bufB : bufA, lm, lq, wq * 64);
    mlp_pair<3>(inpA, F0[2], F0[3], b0s[2], b0s[3], role ? bufB : bufA, lm, lq, wq * 64 + 32);
    {
      float T2 = mm5b(iA0, iB0, That, That);
      float X  = -1.13859f * That + 0.9901f * T2;
      float Zp = mm5b(iA0, iB0, T2, X)
               + 1.03702f * gdel - 0.21179f * That + 0.09756f * T2;
      Zv = Zp;
      float TZ = mm5b(iA0, iB0, That, Zp);
      Yv = 0.87f * TZ + 0.93f * Zp;
    }
    __syncthreads();
    // p2: layer1 + NS1
    mlp_pair<4>(role ? bufB : bufA, F1[0], F1[1], b1s[0], b1s[1],
                role ? bufD : bufC, lm, lq, wq * 64);
    mlp_pair<4>(role ? bufB : bufA, F1[2], F1[3], b1s[2], b1s[3],
                role ? bufD : bufC, lm, lq, wq * 64 + 32);
    NS_ITER;
    __syncthreads();
    // p3: drift d2 + NS2
    if (!role) {
      mlp_pair<4>(bufC, F2[0], F2[1], b2s[0], b2s[1], bufA, lm, lq, wq * 64);
      mlp_pair<4>(bufC, F2[2], F2[3], b2s[2], b2s[3], bufA, lm, lq, wq * 64 + 32);
    }
    NS_ITER;
    __syncthreads();
    // p5: per-lane heads + NS3 + expm + exp-map
    if (glane < 15) {
      float accD = b3r, accG = g2r;
      const uint4* w3r = (const uint4*)(w3s + glane * 68);
      const uint4* g2rr = (const uint4*)(gw2s + glane * 68);
#pragma unroll
      for (int c = 0; c < 16; c++) {
        uint4 avD = *(const uint4*)((const uint*)(bufA + c * 128 + ge * 8));
        uint4 avG = *(const uint4*)((const uint*)(bufD + c * 128 + ge * 8));
        DOT4(accD, w3r[c], avD);
        DOT4(accG, g2rr[c], avG);
      }
      coeff_s[ge * 16 + glane] = 0.2f * accD;
      float sp = (accG > 20.f) ? accG : __logf(1.f + __expf(accG));
      coeff2_s[ge * 16 + glane] = sp * dwv;
    }
    NS_ITER;
    float L = Yv * sqrtf(0.5f * tr);
    {
      float av;
      if (gii == gjj) av = coeff_s[ge * 16 + gii] + coeff2_s[ge * 16 + gii];
      else {
        int p = gii < gjj ? gii : gjj, qq = gii < gjj ? gjj : gii;
        int i5 = 5 + (p * (9 - p)) / 2 + (qq - p - 1);
        av = (coeff_s[ge * 16 + i5] + coeff2_s[ge * 16 + i5]) * 0.70710678f;
      }
      float a2 = mm5b(iA0, iB0, av, av);
      float a3 = mm5b(iA0, iB0, a2, av);
      float q1 = gdel * 0.16666667f + av * 0.04166667f
               + a2 * 0.00833333f + a3 * 0.00138889f;
      float M = gdel + av + 0.5f * a2 + mm5b(iA0, iB0, a3, q1);
      float P2 = mm5b(iA0, iB0, L, M);
      float S2 = mm5b(iA0, iB0, P2, L);
      S2 = 0.5f * (S2 + bpf(iT0, S2));
      if (glane < 25) {
        sig_s[ge * 28 + gli] = S2;
        inpA[(gli >> 3) * 128 + ge * 8 + (gli & 7)] = (_Float16)S2;
      }
    }
    __syncthreads();
  }

  for (int idx = tid; idx < 200; idx += 256) {
    int e = idx / 25, k = idx % 25;
    outp[(eb + e) * 25 + k] = sig_s[e * 28 + k];
  }
}

extern "C" void kernel_launch(void* const* d_in, const int* in_sizes, int n_in,
                              void* d_out, int out_size, void* d_ws, size_t ws_size,
                              hipStream_t stream) {
  const float* ctp = (const float*)d_in[0];
  const float* dWp = (const float*)d_in[1];
  const float* wih = (const float*)d_in[2];
  const float* whh = (const float*)d_in[3];
  const float* gb  = (const float*)d_in[4];
  const float* gbn = (const float*)d_in[5];
  const float* pw  = (const float*)d_in[6];
  const float* pb  = (const float*)d_in[7];
  const float* dw0 = (const float*)d_in[8];
  const float* db0 = (const float*)d_in[9];
  const float* dw1 = (const float*)d_in[10];
  const float* db1 = (const float*)d_in[11];
  const float* dw2 = (const float*)d_in[12];
  const float* db2 = (const float*)d_in[13];
  const float* dw3 = (const float*)d_in[14];
  const float* db3 = (const float*)d_in[15];
  const float* gw0 = (const float*)d_in[16];
  const float* gb0 = (const float*)d_in[17];
  const float* gw1 = (const float*)d_in[18];
  const float* gb1 = (const float*)d_in[19];
  const float* gw2 = (const float*)d_in[20];
  const float* gb2 = (const float*)d_in[21];
  uint* wsu = (uint*)d_ws;
  _Float16* ctxg = (_Float16*)(wsu + OFF_CTXG);

  hipLaunchKernelGGL(prep_kernel, dim3(288), dim3(256), 0, stream,
                     wih, whh, pw, dw0, dw1, dw2, gw0, gw1, dw3, gw2, wsu);
  hipLaunchKernelGGL(gru_kernel, dim3(256), dim3(512), 0, stream,
                     ctp, wsu, gb, gbn, pb, ctxg);
  hipLaunchKernelGGL(sde_kernel, dim3(512), dim3(256), 0, stream,
                     ctp, dWp, wsu, db0, db1, db2, db3,
                     gb0, gb1, gb2, (float*)d_out);
}

// Round 10
// 194.416 us; speedup vs baseline: 1.0287x; 1.0287x over previous
//
#include <hip/hip_runtime.h>
#include <hip/hip_bf16.h>

typedef unsigned int uint;

#define T_STEPS 32

typedef _Float16 half8 __attribute__((ext_vector_type(8)));
typedef float    f32x4 __attribute__((ext_vector_type(4)));

union FB { uint4 u4; half8 h; };

__device__ inline uint pack2f(float a, float b) {
  _Float16 ha = (_Float16)a, hb = (_Float16)b;
  unsigned short ua, ub;
  __builtin_memcpy(&ua, &ha, 2);
  __builtin_memcpy(&ub, &hb, 2);
  return (uint)ua | ((uint)ub << 16);
}

__device__ inline float sigm(float x) { return 1.f / (1.f + __expf(-x)); }
__device__ inline float tanh_f(float x) {
  float ax = fabsf(x);
  float e = __expf(2.f * ax);
  float t = 1.f - 2.f / (e + 1.f);
  return copysignf(t, x);
}
__device__ inline float silu_f(float x) { return x / (1.f + __expf(-x)); }

__device__ inline float map89(const float* __restrict__ W, int u, int k) {
  if (k < 25) return W[u * 89 + k];
  if (k < 32) return 0.f;
  return W[u * 89 + k - 7];   // ctx part: 25 + (k-32)
}

// MLP dual-slot phase: A-frags in LDS, B-frags in VGPRs.
template <int KT>
__device__ inline void mlp_pair(const _Float16* __restrict__ aA,
                                const FB* B0, const FB* B1,
                                float bias0, float bias1,
                                _Float16* __restrict__ outA,
                                int lm, int lq, int ubase) {
  f32x4 c0 = {0.f, 0.f, 0.f, 0.f}, c1 = {0.f, 0.f, 0.f, 0.f};
#pragma unroll
  for (int kt = 0; kt < KT; kt++) {
    half8 a = *(const half8*)(aA + ((kt * 4 + lq) * 16 + lm) * 8);
    c0 = __builtin_amdgcn_mfma_f32_16x16x32_f16(a, B0[kt].h, c0, 0, 0, 0);
    c1 = __builtin_amdgcn_mfma_f32_16x16x32_f16(a, B1[kt].h, c1, 0, 0, 0);
  }
  int u0 = ubase + lm, u1 = ubase + 16 + lm;
  int base0 = (u0 >> 3) * 128 + (u0 & 7);
  int base1 = (u1 >> 3) * 128 + (u1 & 7);
#pragma unroll
  for (int s = 0; s < 4; s++) {
    outA[base0 + (lq * 4 + s) * 8] = (_Float16)silu_f(c0[s] + bias0);
    outA[base1 + (lq * 4 + s) * 8] = (_Float16)silu_f(c1[s] + bias1);
  }
}

__device__ inline f32x4 head4(const _Float16* __restrict__ aA, const FB* H,
                              int lm, int lq) {
  f32x4 c = {0.f, 0.f, 0.f, 0.f};
#pragma unroll
  for (int kt = 0; kt < 4; kt++) {
    half8 a = *(const half8*)(aA + ((kt * 4 + lq) * 16 + lm) * 8);
    c = __builtin_amdgcn_mfma_f32_16x16x32_f16(a, H[kt].h, c, 0, 0, 0);
  }
  return c;
}

// ---- 5x5 wave-parallel matmul via raw ds_bpermute (hoisted addresses) ----
__device__ inline float bpf(int addr, float v) {
  return __int_as_float(__builtin_amdgcn_ds_bpermute(addr, __float_as_int(v)));
}
__device__ inline float mm5b(int iA, int iB, float A, float B) {
  float c = 0.f;
#pragma unroll
  for (int k = 0; k < 5; k++)
    c = fmaf(bpf(iA + 4 * k, A), bpf(iB + 20 * k, B), c);
  return c;
}

#define NS_ITER do { \
  float P_  = mm5b(iA0, iB0, Zv, Yv); \
  float Tm_ = 1.5f * gdel - 0.5f * P_; \
  float Yn_ = mm5b(iA0, iB0, Yv, Tm_); \
  float Zn_ = mm5b(iA0, iB0, Tm_, Zv); \
  Yv = Yn_; Zv = Zn_; } while (0)

// ======================= fused GRU + SDE (single launch) =======================
// grid 256 x 512; block owns 16 batch rows. All weights gathered in-kernel.
__global__ __launch_bounds__(512) void fused_kernel(
    const float* __restrict__ ctp, const float* __restrict__ dWp,
    const float* __restrict__ wih, const float* __restrict__ whh,
    const float* __restrict__ gbias, const float* __restrict__ gbn,
    const float* __restrict__ pw, const float* __restrict__ projb,
    const float* __restrict__ dw0, const float* __restrict__ db0,
    const float* __restrict__ dw1, const float* __restrict__ db1,
    const float* __restrict__ dw2, const float* __restrict__ db2,
    const float* __restrict__ dw3, const float* __restrict__ b3,
    const float* __restrict__ gw0, const float* __restrict__ gb0,
    const float* __restrict__ gw1, const float* __restrict__ gb1,
    const float* __restrict__ gw2, const float* __restrict__ gb2,
    float* __restrict__ outp) {
  __shared__ __align__(16) _Float16 bigbuf[16384];           // 32KB: x2 / SDE bufs
  __shared__ __align__(16) _Float16 hf[2][4][4][16][8];      // 8KB dbuf h A-frags
  __shared__ float sig_s[16 * 28];
  __shared__ float coeff_s[256];
  __shared__ float coeff2_s[256];
  const int tid = threadIdx.x;
  const int rb = blockIdx.x * 16;
  uint* bigu = (uint*)bigbuf;

  // ---- stage symmetrized features as A-frags (x2 = bigbuf) ----
  for (int idx = tid; idx < T_STEPS * 16 * 16; idx += 512) {
    int k2 = idx & 15, r = (idx >> 4) & 15, t = idx >> 8;
    const float* base = ctp + ((rb + r) * T_STEPS + t) * 25;
    int k0 = 2 * k2;
    float v0 = 0.f, v1 = 0.f;
    if (k0 < 25)     { int i5 = k0 / 5,     j5 = k0 % 5;     v0 = 0.5f * (base[i5*5+j5] + base[j5*5+i5]); }
    if (k0 + 1 < 25) { int i5 = (k0+1) / 5, j5 = (k0+1) % 5; v1 = 0.5f * (base[i5*5+j5] + base[j5*5+i5]); }
    int q = k2 >> 2, jh = k2 & 3;
    bigu[((t * 4 + q) * 16 + r) * 4 + jh] = pack2f(v0, v1);
  }

  const int w = tid >> 6, l = tid & 63;
  const int lm = l & 15, lq = l >> 4;
  const int u = w * 16 + lm;
  const int ku = u >> 5, qu = (u >> 3) & 3, ju = u & 7;

  // ---- GRU B-frag gather (direct from wih/whh) ----
  FB Bf[3][5];
#pragma unroll
  for (int gi = 0; gi < 3; gi++) {
    int row = gi * 128 + u;
#pragma unroll
    for (int kt = 0; kt < 5; kt++) {
      uint4 v;
#pragma unroll
      for (int i = 0; i < 4; i++) {
        int k = kt * 32 + lq * 8 + 2 * i;
        float a, b;
        if (kt == 0) {
          a = (k     < 25) ? wih[row * 25 + k]     : 0.f;
          b = (k + 1 < 25) ? wih[row * 25 + k + 1] : 0.f;
        } else {
          int kh = k - 32;
          a = whh[row * 128 + kh];
          b = whh[row * 128 + kh + 1];
        }
        ((uint*)&v)[i] = pack2f(a, b);
      }
      Bf[gi][kt].u4 = v;
    }
  }
  const float br = gbias[u], bz = gbias[128 + u], bg = gbias[256 + u], bn = gbn[u];
  float hprev[4] = {0.f, 0.f, 0.f, 0.f};
  __syncthreads();

  // ---- GRU t-loop (1 barrier/step, x-part software-pipelined) ----
  f32x4 z4 = {0.f, 0.f, 0.f, 0.f};
  half8 axn = *(const half8*)(bigbuf + ((0 * 4 + lq) * 16 + lm) * 8);
  f32x4 pxr = __builtin_amdgcn_mfma_f32_16x16x32_f16(axn, Bf[0][0].h, z4, 0, 0, 0);
  f32x4 pxz = __builtin_amdgcn_mfma_f32_16x16x32_f16(axn, Bf[1][0].h, z4, 0, 0, 0);
  f32x4 pxg = __builtin_amdgcn_mfma_f32_16x16x32_f16(axn, Bf[2][0].h, z4, 0, 0, 0);
  for (int t = 0; t < T_STEPS; t++) {
    f32x4 cr = pxr, cz = pxz, cgv = pxg;
    f32x4 ch = {0.f, 0.f, 0.f, 0.f};
    if (t > 0) {
      const int p = t & 1;
#pragma unroll
      for (int kk = 0; kk < 4; kk++) {
        half8 ah = *(const half8*)(&hf[p][kk][lq][lm][0]);
        cr = __builtin_amdgcn_mfma_f32_16x16x32_f16(ah, Bf[0][1 + kk].h, cr, 0, 0, 0);
        cz = __builtin_amdgcn_mfma_f32_16x16x32_f16(ah, Bf[1][1 + kk].h, cz, 0, 0, 0);
        ch = __builtin_amdgcn_mfma_f32_16x16x32_f16(ah, Bf[2][1 + kk].h, ch, 0, 0, 0);
      }
    }
    if (t < T_STEPS - 1) {   // prefetch next step's x-part (independent of h)
      axn = *(const half8*)(bigbuf + (((t + 1) * 4 + lq) * 16 + lm) * 8);
      pxr = __builtin_amdgcn_mfma_f32_16x16x32_f16(axn, Bf[0][0].h, z4, 0, 0, 0);
      pxz = __builtin_amdgcn_mfma_f32_16x16x32_f16(axn, Bf[1][0].h, z4, 0, 0, 0);
      pxg = __builtin_amdgcn_mfma_f32_16x16x32_f16(axn, Bf[2][0].h, z4, 0, 0, 0);
    }
    const int wp = (t + 1) & 1;
#pragma unroll
    for (int s = 0; s < 4; s++) {
      float r = sigm(cr[s] + br);
      float z = sigm(cz[s] + bz);
      float g = tanh_f(cgv[s] + bg + r * (ch[s] + bn));
      float hn = (1.f - z) * g + z * hprev[s];
      hprev[s] = hn;
      hf[wp][ku][qu][lq * 4 + s][ju] = (_Float16)hn;
    }
    __syncthreads();
  }

  // ---- SDE B-frag gather (registers), role-split ----
  const int role = w >> 2;                 // 0: drift (waves 0-3), 1: diff (4-7)
  const int wbq = w & 3;
  FB F0[2][3], F1[2][4], F2[2][4], Pf[4], Hf[4];
  {
    const float* W0 = role ? gw0 : dw0;
    const float* W1 = role ? gw1 : dw1;
    const float* W2 = role ? gw1 : dw2;    // diff: dummy (never used)
#pragma unroll
    for (int s = 0; s < 2; s++) {
      int slot = wbq * 2 + s;
      int us = slot * 16 + lm;
#pragma unroll
      for (int kt = 0; kt < 3; kt++) {
        uint4 v;
#pragma unroll
        for (int i = 0; i < 4; i++) {
          int k = kt * 32 + lq * 8 + 2 * i;
          ((uint*)&v)[i] = pack2f(map89(W0, us, k), map89(W0, us, k + 1));
        }
        F0[s][kt].u4 = v;
      }
#pragma unroll
      for (int kt = 0; kt < 4; kt++) {
        uint4 v1, v2;
#pragma unroll
        for (int i = 0; i < 4; i++) {
          int k = kt * 32 + lq * 8 + 2 * i;
          ((uint*)&v1)[i] = pack2f(W1[us * 128 + k], W1[us * 128 + k + 1]);
          ((uint*)&v2)[i] = pack2f(W2[us * 128 + k], W2[us * 128 + k + 1]);
        }
        F1[s][kt].u4 = v1;
        F2[s][kt].u4 = v2;
      }
    }
  }
  if (w < 4) {                             // proj B-frags
#pragma unroll
    for (int kt = 0; kt < 4; kt++) {
      uint4 v;
#pragma unroll
      for (int i = 0; i < 4; i++) {
        int k = kt * 32 + lq * 8 + 2 * i;
        ((uint*)&v)[i] = pack2f(pw[u * 128 + k], pw[u * 128 + k + 1]);
      }
      Pf[kt].u4 = v;
    }
  }
  if (w == 0 || w == 4) {                  // head B-frags (N pad 15->16)
    const float* WH = (w == 0) ? dw3 : gw2;
#pragma unroll
    for (int kt = 0; kt < 4; kt++) {
      uint4 v;
#pragma unroll
      for (int i = 0; i < 4; i++) {
        int k = kt * 32 + lq * 8 + 2 * i;
        float a = (lm < 15) ? WH[lm * 128 + k]     : 0.f;
        float b = (lm < 15) ? WH[lm * 128 + k + 1] : 0.f;
        ((uint*)&v)[i] = pack2f(a, b);
      }
      Hf[kt].u4 = v;
    }
  }
  float b0s[2], b1s[2], b2s[2];
#pragma unroll
  for (int s = 0; s < 2; s++) {
    int us = wbq * 32 + s * 16 + lm;
    b0s[s] = role ? gb0[us] : db0[us];
    b1s[s] = role ? gb1[us] : db1[us];
    b2s[s] = role ? 0.f : db2[us];
  }
  const int oc = (lm < 15) ? lm : 0;
  const float hb = (w == 0) ? b3[oc] : ((w == 4) ? gb2[oc] : 0.f);

  _Float16* inpA = bigbuf;          // 3 ktiles (k: 0-24 sigma | pad | 32-95 ctx)
  _Float16* bufA = bigbuf + 1536;   // drift d0 out / d2 out
  _Float16* bufB = bigbuf + 3584;   // diff g0 out
  _Float16* bufC = bigbuf + 5632;   // drift d1 out
  _Float16* bufD = bigbuf + 7680;   // diff g1 out

  // proj via MFMA (waves 0-3): ctx -> inpA ctx part
  if (w < 4) {
    f32x4 c = {0.f, 0.f, 0.f, 0.f};
#pragma unroll
    for (int kt = 0; kt < 4; kt++) {
      half8 a = *(const half8*)(&hf[0][kt][lq][lm][0]);
      c = __builtin_amdgcn_mfma_f32_16x16x32_f16(a, Pf[kt].h, c, 0, 0, 0);
    }
    const float pbv = projb[u];
    int kk = 32 + u, base = (kk >> 3) * 128 + (kk & 7);
#pragma unroll
    for (int s = 0; s < 4; s++)
      inpA[base + (lq * 4 + s) * 8] = (_Float16)(c[s] + pbv);
  }
  // sigma init + pad
  for (int idx = tid; idx < 400; idx += 512) {
    int e = idx / 25, k = idx % 25;
    int i5 = k / 5, j5 = k % 5;
    const float* base = ctp + ((rb + e) * T_STEPS + 31) * 25;
    float v = 0.5f * (base[i5 * 5 + j5] + base[j5 * 5 + i5]);
    sig_s[e * 28 + k] = v;
    inpA[(k >> 3) * 128 + e * 8 + (k & 7)] = (_Float16)v;
  }
  if (tid < 112) {
    int e = tid / 7, p = 25 + tid % 7;
    inpA[(p >> 3) * 128 + e * 8 + (p & 7)] = (_Float16)0.f;
  }
  // geometry lane constants
  const int ge = tid >> 5, glane = tid & 31;
  const int gli = (glane < 25) ? glane : 0;
  const int gii = gli / 5, gjj = gli % 5;
  const float gdel = (gii == gjj) ? 1.f : 0.f;
  const int gbase = (l & 32) << 2;
  const int iA0 = gbase + gii * 20;
  const int iB0 = gbase + gjj * 4;
  const int iT0 = gbase + (gjj * 5 + gii) * 4;
  __syncthreads();

  // ---- SDE step loop: 5 barriers/step; sqrt = cheb4 + 3 NS, overlapped ----
  for (int st = 0; st < 5; st++) {
    float S = sig_s[ge * 28 + gli];
    float tr = 0.f;
#pragma unroll
    for (int d = 0; d < 5; d++) tr += bpf(gbase + 24 * d, S);
    const float That = S * (2.298851f / tr) - 1.068966f * gdel;
    float dwv[4] = {0.f, 0.f, 0.f, 0.f};
    if (w == 4) {
#pragma unroll
      for (int s = 0; s < 4; s++)
        dwv[s] = dWp[((rb + lq * 4 + s) * 5 + st) * 15 + oc];
    }
    float Yv, Zv;
    // p1: d0 || g0  (+ cheb4 preconditioner)
    mlp_pair<3>(inpA, F0[0], F0[1], b0s[0], b0s[1], role ? bufB : bufA, lm, lq, wbq * 32);
    {
      float T2 = mm5b(iA0, iB0, That, That);
      float X  = -1.13859f * That + 0.9901f * T2;
      float Zp = mm5b(iA0, iB0, T2, X)
               + 1.03702f * gdel - 0.21179f * That + 0.09756f * T2;
      Zv = Zp;
      float TZ = mm5b(iA0, iB0, That, Zp);
      Yv = 0.87f * TZ + 0.93f * Zp;
    }
    __syncthreads();
    // p2: d1 || g1  (+ NS1)
    mlp_pair<4>(role ? bufB : bufA, F1[0], F1[1], b1s[0], b1s[1],
                role ? bufD : bufC, lm, lq, wbq * 32);
    NS_ITER;
    __syncthreads();
    // p3: d2 || diff-head  (+ NS2)
    if (!role) {
      mlp_pair<4>(bufC, F2[0], F2[1], b2s[0], b2s[1], bufA, lm, lq, wbq * 32);
    } else if (w == 4) {
      f32x4 c = head4(bufD, Hf, lm, lq);
      if (lm < 15) {
#pragma unroll
        for (int s = 0; s < 4; s++) {
          float acc = c[s] + hb;
          float sp = (acc > 20.f) ? acc : __logf(1.f + __expf(acc));
          coeff2_s[(lq * 4 + s) * 16 + lm] = sp * dwv[s];
        }
      }
    }
    NS_ITER;
    __syncthreads();
    // p4: drift head  (+ NS3, finalize L)
    if (w == 0) {
      f32x4 c = head4(bufA, Hf, lm, lq);
      if (lm < 15) {
#pragma unroll
        for (int s = 0; s < 4; s++)
          coeff_s[(lq * 4 + s) * 16 + lm] = 0.2f * (c[s] + hb);
      }
    }
    NS_ITER;
    float L = Yv * sqrtf(0.5f * tr);
    __syncthreads();
    // p5: tangent build + expm (powers, deg-6) + exp-map + write
    {
      float av;
      if (gii == gjj) av = coeff_s[ge * 16 + gii] + coeff2_s[ge * 16 + gii];
      else {
        int p = gii < gjj ? gii : gjj, qq = gii < gjj ? gjj : gii;
        int i5 = 5 + (p * (9 - p)) / 2 + (qq - p - 1);
        av = (coeff_s[ge * 16 + i5] + coeff2_s[ge * 16 + i5]) * 0.70710678f;
      }
      float a2 = mm5b(iA0, iB0, av, av);
      float a3 = mm5b(iA0, iB0, a2, av);
      float q1 = gdel * 0.16666667f + av * 0.04166667f
               + a2 * 0.00833333f + a3 * 0.00138889f;
      float M = gdel + av + 0.5f * a2 + mm5b(iA0, iB0, a3, q1);
      float P2 = mm5b(iA0, iB0, L, M);
      float S2 = mm5b(iA0, iB0, P2, L);
      S2 = 0.5f * (S2 + bpf(iT0, S2));
      if (glane < 25) {
        sig_s[ge * 28 + gli] = S2;
        inpA[(gli >> 3) * 128 + ge * 8 + (gli & 7)] = (_Float16)S2;
      }
    }
    __syncthreads();
  }

  for (int idx = tid; idx < 400; idx += 512) {
    int e = idx / 25, k = idx % 25;
    outp[(rb + e) * 25 + k] = sig_s[e * 28 + k];
  }
}

extern "C" void kernel_launch(void* const* d_in, const int* in_sizes, int n_in,
                              void* d_out, int out_size, void* d_ws, size_t ws_size,
                              hipStream_t stream) {
  const float* ctp = (const float*)d_in[0];
  const float* dWp = (const float*)d_in[1];
  const float* wih = (const float*)d_in[2];
  const float* whh = (const float*)d_in[3];
  const float* gb  = (const float*)d_in[4];
  const float* gbn = (const float*)d_in[5];
  const float* pw  = (const float*)d_in[6];
  const float* pb  = (const float*)d_in[7];
  const float* dw0 = (const float*)d_in[8];
  const float* db0 = (const float*)d_in[9];
  const float* dw1 = (const float*)d_in[10];
  const float* db1 = (const float*)d_in[11];
  const float* dw2 = (const float*)d_in[12];
  const float* db2 = (const float*)d_in[13];
  const float* dw3 = (const float*)d_in[14];
  const float* db3 = (const float*)d_in[15];
  const float* gw0 = (const float*)d_in[16];
  const float* gb0 = (const float*)d_in[17];
  const float* gw1 = (const float*)d_in[18];
  const float* gb1 = (const float*)d_in[19];
  const float* gw2 = (const float*)d_in[20];
  const float* gb2 = (const float*)d_in[21];

  hipLaunchKernelGGL(fused_kernel, dim3(256), dim3(512), 0, stream,
                     ctp, dWp, wih, whh, gb, gbn, pw, pb,
                     dw0, db0, dw1, db1, dw2, db2, dw3, db3,
                     gw0, gb0, gw1, gb1, gw2, gb2, (float*)d_out);
}

// Round 11
// 165.727 us; speedup vs baseline: 1.2068x; 1.1731x over previous
//
#include <hip/hip_runtime.h>
#include <hip/hip_bf16.h>

typedef unsigned int uint;

#define T_STEPS 32

// ---- workspace dword offsets ----
#define OFF_WB    0        // 30720: GRU B-frags
#define OFF_PJB   30720    // 4096 : proj B-frags (waves 0-3)
#define OFF_D0B   34816    // 6144 : drift_w0 B-frags (8 slots x 3 kt)
#define OFF_D1B   40960    // 8192
#define OFF_D2B   49152    // 8192
#define OFF_G0B   57344    // 6144
#define OFF_G1B   63488    // 8192
#define OFF_W3B   71680    // 1024 : drift_w3 head (N pad 15->16)
#define OFF_G2B   72704    // 1024 : diff_w2 head

typedef _Float16 half8 __attribute__((ext_vector_type(8)));
typedef float    f32x4 __attribute__((ext_vector_type(4)));

union FB { uint4 u4; half8 h; };

__device__ inline uint pack2f(float a, float b) {
  _Float16 ha = (_Float16)a, hb = (_Float16)b;
  unsigned short ua, ub;
  __builtin_memcpy(&ua, &ha, 2);
  __builtin_memcpy(&ub, &hb, 2);
  return (uint)ua | ((uint)ub << 16);
}

// ---- fast activations: Pade(3/2) tanh + clamp, raw v_rcp ----
__device__ inline float rcpf(float x) {
#if __has_builtin(__builtin_amdgcn_rcpf)
  return __builtin_amdgcn_rcpf(x);
#else
  return 1.f / x;
#endif
}
__device__ inline float tanh_fast(float x) {
  float t = x * x;
  float num = x * (27.f + t);
  float den = fmaf(t, 9.f, 27.f);
  float r = num * rcpf(den);
  return fminf(1.f, fmaxf(-1.f, r));
}
__device__ inline float sigm(float x) { return fmaf(tanh_fast(0.5f * x), 0.5f, 0.5f); }
__device__ inline float silu_f(float x) { return x * sigm(x); }

__device__ inline float map89(const float* __restrict__ W, int u, int k) {
  if (k < 25) return W[u * 89 + k];
  if (k < 32) return 0.f;
  return W[u * 89 + k - 7];   // ctx part: 25 + (k-32)
}

// ======================= weight pre-pack =======================
__global__ __launch_bounds__(256) void prep_kernel(
    const float* __restrict__ wih, const float* __restrict__ whh,
    const float* __restrict__ pw,
    const float* __restrict__ dw0, const float* __restrict__ dw1,
    const float* __restrict__ dw2, const float* __restrict__ gw0,
    const float* __restrict__ gw1, const float* __restrict__ dw3,
    const float* __restrict__ gw2, uint* __restrict__ wsu) {
  int id = blockIdx.x * 256 + threadIdx.x;
  if (id < 30720) {
    int i = id & 3, l = (id >> 2) & 63, t3 = id >> 8;
    int kt = t3 % 5, wg = t3 / 5;
    int w = wg / 3, gi = wg % 3;
    int row = gi * 128 + w * 16 + (l & 15);
    int k = ((l >> 4) << 3) + i * 2;
    float a, b;
    if (kt == 0) {
      a = (k     < 25) ? wih[row * 25 + k]     : 0.f;
      b = (k + 1 < 25) ? wih[row * 25 + k + 1] : 0.f;
    } else {
      int kh = (kt - 1) * 32 + k;
      a = whh[row * 128 + kh];
      b = whh[row * 128 + kh + 1];
    }
    wsu[OFF_WB + id] = pack2f(a, b);
  } else if (id < 34816) {               // proj B-frags: (w*4+kt)
    int t = id - 30720;
    int i = t & 3, l = (t >> 2) & 63, wkt = t >> 8;
    int kt = wkt & 3, w = wkt >> 2;
    int u = w * 16 + (l & 15);
    int k = kt * 32 + ((l >> 4) << 3) + i * 2;
    wsu[OFF_PJB + t] = pack2f(pw[u * 128 + k], pw[u * 128 + k + 1]);
  } else if (id < 40960) {               // drift_w0 (89-in, 8 slots x 3 kt)
    int t = id - 34816;
    int i = t & 3, l = (t >> 2) & 63, wkt = t >> 8;
    int kt = wkt % 3, w = wkt / 3;
    int u = w * 16 + (l & 15);
    int k = kt * 32 + ((l >> 4) << 3) + i * 2;
    wsu[OFF_D0B + t] = pack2f(map89(dw0, u, k), map89(dw0, u, k + 1));
  } else if (id < 49152) {               // drift_w1
    int t = id - 40960;
    int i = t & 3, l = (t >> 2) & 63, wkt = t >> 8;
    int kt = wkt & 3, w = wkt >> 2;
    int u = w * 16 + (l & 15);
    int k = kt * 32 + ((l >> 4) << 3) + i * 2;
    wsu[OFF_D1B + t] = pack2f(dw1[u * 128 + k], dw1[u * 128 + k + 1]);
  } else if (id < 57344) {               // drift_w2
    int t = id - 49152;
    int i = t & 3, l = (t >> 2) & 63, wkt = t >> 8;
    int kt = wkt & 3, w = wkt >> 2;
    int u = w * 16 + (l & 15);
    int k = kt * 32 + ((l >> 4) << 3) + i * 2;
    wsu[OFF_D2B + t] = pack2f(dw2[u * 128 + k], dw2[u * 128 + k + 1]);
  } else if (id < 63488) {               // diff_w0 (89-in)
    int t = id - 57344;
    int i = t & 3, l = (t >> 2) & 63, wkt = t >> 8;
    int kt = wkt % 3, w = wkt / 3;
    int u = w * 16 + (l & 15);
    int k = kt * 32 + ((l >> 4) << 3) + i * 2;
    wsu[OFF_G0B + t] = pack2f(map89(gw0, u, k), map89(gw0, u, k + 1));
  } else if (id < 71680) {               // diff_w1
    int t = id - 63488;
    int i = t & 3, l = (t >> 2) & 63, wkt = t >> 8;
    int kt = wkt & 3, w = wkt >> 2;
    int u = w * 16 + (l & 15);
    int k = kt * 32 + ((l >> 4) << 3) + i * 2;
    wsu[OFF_G1B + t] = pack2f(gw1[u * 128 + k], gw1[u * 128 + k + 1]);
  } else if (id < 72704) {               // drift_w3 head (15 outs, pad 16)
    int t = id - 71680;
    int i = t & 3, l = (t >> 2) & 63, kt = t >> 8;
    int o = l & 15;
    int k = kt * 32 + ((l >> 4) << 3) + i * 2;
    float a = (o < 15) ? dw3[o * 128 + k]     : 0.f;
    float b = (o < 15) ? dw3[o * 128 + k + 1] : 0.f;
    wsu[OFF_W3B + t] = pack2f(a, b);
  } else if (id < 73728) {               // diff_w2 head
    int t = id - 72704;
    int i = t & 3, l = (t >> 2) & 63, kt = t >> 8;
    int o = l & 15;
    int k = kt * 32 + ((l >> 4) << 3) + i * 2;
    float a = (o < 15) ? gw2[o * 128 + k]     : 0.f;
    float b = (o < 15) ? gw2[o * 128 + k + 1] : 0.f;
    wsu[OFF_G2B + t] = pack2f(a, b);
  }
}

// MLP dual-slot phase: A-frags in LDS, B-frags in VGPRs.
template <int KT>
__device__ inline void mlp_pair(const _Float16* __restrict__ aA,
                                const FB* B0, const FB* B1,
                                float bias0, float bias1,
                                _Float16* __restrict__ outA,
                                int lm, int lq, int ubase) {
  f32x4 c0 = {0.f, 0.f, 0.f, 0.f}, c1 = {0.f, 0.f, 0.f, 0.f};
#pragma unroll
  for (int kt = 0; kt < KT; kt++) {
    half8 a = *(const half8*)(aA + ((kt * 4 + lq) * 16 + lm) * 8);
    c0 = __builtin_amdgcn_mfma_f32_16x16x32_f16(a, B0[kt].h, c0, 0, 0, 0);
    c1 = __builtin_amdgcn_mfma_f32_16x16x32_f16(a, B1[kt].h, c1, 0, 0, 0);
  }
  int u0 = ubase + lm, u1 = ubase + 16 + lm;
  int base0 = (u0 >> 3) * 128 + (u0 & 7);
  int base1 = (u1 >> 3) * 128 + (u1 & 7);
#pragma unroll
  for (int s = 0; s < 4; s++) {
    outA[base0 + (lq * 4 + s) * 8] = (_Float16)silu_f(c0[s] + bias0);
    outA[base1 + (lq * 4 + s) * 8] = (_Float16)silu_f(c1[s] + bias1);
  }
}

__device__ inline f32x4 head4(const _Float16* __restrict__ aA, const FB* H,
                              int lm, int lq) {
  f32x4 c = {0.f, 0.f, 0.f, 0.f};
#pragma unroll
  for (int kt = 0; kt < 4; kt++) {
    half8 a = *(const half8*)(aA + ((kt * 4 + lq) * 16 + lm) * 8);
    c = __builtin_amdgcn_mfma_f32_16x16x32_f16(a, H[kt].h, c, 0, 0, 0);
  }
  return c;
}

// ---- 5x5 wave-parallel matmul via raw ds_bpermute (hoisted addresses) ----
__device__ inline float bpf(int addr, float v) {
  return __int_as_float(__builtin_amdgcn_ds_bpermute(addr, __float_as_int(v)));
}
__device__ inline float mm5b(int iA, int iB, float A, float B) {
  float c = 0.f;
#pragma unroll
  for (int k = 0; k < 5; k++)
    c = fmaf(bpf(iA + 4 * k, A), bpf(iB + 20 * k, B), c);
  return c;
}

#define NS_ITER do { \
  float P_  = mm5b(iA0, iB0, Zv, Yv); \
  float Tm_ = 1.5f * gdel - 0.5f * P_; \
  float Yn_ = mm5b(iA0, iB0, Yv, Tm_); \
  float Zn_ = mm5b(iA0, iB0, Tm_, Zv); \
  Yv = Yn_; Zv = Zn_; } while (0)

// ======================= fused GRU + SDE =======================
// grid 256 x 512; block owns 16 batch rows.
__global__ __launch_bounds__(512) void fused_kernel(
    const float* __restrict__ ctp, const float* __restrict__ dWp,
    const uint* __restrict__ wsu,
    const float* __restrict__ gbias, const float* __restrict__ gbn,
    const float* __restrict__ projb,
    const float* __restrict__ db0, const float* __restrict__ db1,
    const float* __restrict__ db2, const float* __restrict__ b3,
    const float* __restrict__ gb0, const float* __restrict__ gb1,
    const float* __restrict__ gb2, float* __restrict__ outp) {
  __shared__ __align__(16) _Float16 bigbuf[16384];           // 32KB: x2 / SDE bufs
  __shared__ __align__(16) _Float16 hf[2][4][4][16][8];      // 8KB dbuf h A-frags
  __shared__ float sig_s[16 * 28];
  __shared__ float coeff_s[256];
  __shared__ float coeff2_s[256];
  const int tid = threadIdx.x;
  const int rb = blockIdx.x * 16;
  uint* bigu = (uint*)bigbuf;

  // ---- stage symmetrized features as A-frags (x2 = bigbuf) ----
  for (int idx = tid; idx < T_STEPS * 16 * 16; idx += 512) {
    int k2 = idx & 15, r = (idx >> 4) & 15, t = idx >> 8;
    const float* base = ctp + ((rb + r) * T_STEPS + t) * 25;
    int k0 = 2 * k2;
    float v0 = 0.f, v1 = 0.f;
    if (k0 < 25)     { int i5 = k0 / 5,     j5 = k0 % 5;     v0 = 0.5f * (base[i5*5+j5] + base[j5*5+i5]); }
    if (k0 + 1 < 25) { int i5 = (k0+1) / 5, j5 = (k0+1) % 5; v1 = 0.5f * (base[i5*5+j5] + base[j5*5+i5]); }
    int q = k2 >> 2, jh = k2 & 3;
    bigu[((t * 4 + q) * 16 + r) * 4 + jh] = pack2f(v0, v1);
  }

  const int w = tid >> 6, l = tid & 63;
  const int lm = l & 15, lq = l >> 4;
  const int u = w * 16 + lm;
  const int ku = u >> 5, qu = (u >> 3) & 3, ju = u & 7;
  FB Bf[3][5];
  const uint4* wb4p = (const uint4*)(wsu + OFF_WB);
#pragma unroll
  for (int gi = 0; gi < 3; gi++)
#pragma unroll
    for (int kt = 0; kt < 5; kt++)
      Bf[gi][kt].u4 = wb4p[((w * 3 + gi) * 5 + kt) * 64 + l];
  const float br = gbias[u], bz = gbias[128 + u], bg = gbias[256 + u], bn = gbn[u];
  float hprev[4] = {0.f, 0.f, 0.f, 0.f};
  __syncthreads();

  // ---- GRU t-loop (1 barrier/step, x-part software-pipelined) ----
  f32x4 z4 = {0.f, 0.f, 0.f, 0.f};
  half8 axn = *(const half8*)(bigbuf + ((0 * 4 + lq) * 16 + lm) * 8);
  f32x4 pxr = __builtin_amdgcn_mfma_f32_16x16x32_f16(axn, Bf[0][0].h, z4, 0, 0, 0);
  f32x4 pxz = __builtin_amdgcn_mfma_f32_16x16x32_f16(axn, Bf[1][0].h, z4, 0, 0, 0);
  f32x4 pxg = __builtin_amdgcn_mfma_f32_16x16x32_f16(axn, Bf[2][0].h, z4, 0, 0, 0);
  for (int t = 0; t < T_STEPS; t++) {
    f32x4 cr = pxr, cz = pxz, cgv = pxg;
    f32x4 ch = {0.f, 0.f, 0.f, 0.f};
    if (t > 0) {
      const int p = t & 1;
#pragma unroll
      for (int kk = 0; kk < 4; kk++) {
        half8 ah = *(const half8*)(&hf[p][kk][lq][lm][0]);
        cr = __builtin_amdgcn_mfma_f32_16x16x32_f16(ah, Bf[0][1 + kk].h, cr, 0, 0, 0);
        cz = __builtin_amdgcn_mfma_f32_16x16x32_f16(ah, Bf[1][1 + kk].h, cz, 0, 0, 0);
        ch = __builtin_amdgcn_mfma_f32_16x16x32_f16(ah, Bf[2][1 + kk].h, ch, 0, 0, 0);
      }
    }
    if (t < T_STEPS - 1) {   // prefetch next step's x-part (independent of h)
      axn = *(const half8*)(bigbuf + (((t + 1) * 4 + lq) * 16 + lm) * 8);
      pxr = __builtin_amdgcn_mfma_f32_16x16x32_f16(axn, Bf[0][0].h, z4, 0, 0, 0);
      pxz = __builtin_amdgcn_mfma_f32_16x16x32_f16(axn, Bf[1][0].h, z4, 0, 0, 0);
      pxg = __builtin_amdgcn_mfma_f32_16x16x32_f16(axn, Bf[2][0].h, z4, 0, 0, 0);
    }
    const int wp = (t + 1) & 1;
#pragma unroll
    for (int s = 0; s < 4; s++) {
      float r = sigm(cr[s] + br);
      float z = sigm(cz[s] + bz);
      float g = tanh_fast(cgv[s] + bg + r * (ch[s] + bn));
      float hn = (1.f - z) * g + z * hprev[s];
      hprev[s] = hn;
      hf[wp][ku][qu][lq * 4 + s][ju] = (_Float16)hn;
    }
    __syncthreads();
  }

  // ---- SDE B-frag preload (registers), role-split ----
  const int role = w >> 2;                 // 0: drift (waves 0-3), 1: diff (4-7)
  const int wbq = w & 3;
  FB F0[2][3], F1[2][4], F2[2][4], Pf[4], Hf[4];
  {
    const uint4* p0 = (const uint4*)(wsu + (role ? OFF_G0B : OFF_D0B));
    const uint4* p1 = (const uint4*)(wsu + (role ? OFF_G1B : OFF_D1B));
    const uint4* p2 = (const uint4*)(wsu + (role ? OFF_G1B : OFF_D2B)); // diff: dummy
#pragma unroll
    for (int s = 0; s < 2; s++) {
      int slot = wbq * 2 + s;
#pragma unroll
      for (int kt = 0; kt < 3; kt++) F0[s][kt].u4 = p0[(slot * 3 + kt) * 64 + l];
#pragma unroll
      for (int kt = 0; kt < 4; kt++) {
        F1[s][kt].u4 = p1[(slot * 4 + kt) * 64 + l];
        F2[s][kt].u4 = p2[(slot * 4 + kt) * 64 + l];
      }
    }
  }
  if (w < 4) {
#pragma unroll
    for (int kt = 0; kt < 4; kt++)
      Pf[kt].u4 = ((const uint4*)(wsu + OFF_PJB))[(w * 4 + kt) * 64 + l];
  }
  if (w == 0) {
#pragma unroll
    for (int kt = 0; kt < 4; kt++)
      Hf[kt].u4 = ((const uint4*)(wsu + OFF_W3B))[kt * 64 + l];
  } else if (w == 4) {
#pragma unroll
    for (int kt = 0; kt < 4; kt++)
      Hf[kt].u4 = ((const uint4*)(wsu + OFF_G2B))[kt * 64 + l];
  }
  float b0s[2], b1s[2], b2s[2];
#pragma unroll
  for (int s = 0; s < 2; s++) {
    int us = wbq * 32 + s * 16 + lm;
    b0s[s] = role ? gb0[us] : db0[us];
    b1s[s] = role ? gb1[us] : db1[us];
    b2s[s] = role ? 0.f : db2[us];
  }
  const int oc = (lm < 15) ? lm : 0;
  const float hb = (w == 0) ? b3[oc] : ((w == 4) ? gb2[oc] : 0.f);

  _Float16* inpA = bigbuf;          // 3 ktiles (k: 0-24 sigma | pad | 32-95 ctx)
  _Float16* bufA = bigbuf + 1536;   // drift d0 out / d2 out
  _Float16* bufB = bigbuf + 3584;   // diff g0 out
  _Float16* bufC = bigbuf + 5632;   // drift d1 out
  _Float16* bufD = bigbuf + 7680;   // diff g1 out

  // proj via MFMA (waves 0-3): ctx -> inpA ctx part
  if (w < 4) {
    f32x4 c = {0.f, 0.f, 0.f, 0.f};
#pragma unroll
    for (int kt = 0; kt < 4; kt++) {
      half8 a = *(const half8*)(&hf[0][kt][lq][lm][0]);
      c = __builtin_amdgcn_mfma_f32_16x16x32_f16(a, Pf[kt].h, c, 0, 0, 0);
    }
    const float pbv = projb[u];
    int kk = 32 + u, base = (kk >> 3) * 128 + (kk & 7);
#pragma unroll
    for (int s = 0; s < 4; s++)
      inpA[base + (lq * 4 + s) * 8] = (_Float16)(c[s] + pbv);
  }
  // sigma init + pad
  for (int idx = tid; idx < 400; idx += 512) {
    int e = idx / 25, k = idx % 25;
    int i5 = k / 5, j5 = k % 5;
    const float* base = ctp + ((rb + e) * T_STEPS + 31) * 25;
    float v = 0.5f * (base[i5 * 5 + j5] + base[j5 * 5 + i5]);
    sig_s[e * 28 + k] = v;
    inpA[(k >> 3) * 128 + e * 8 + (k & 7)] = (_Float16)v;
  }
  if (tid < 112) {
    int e = tid / 7, p = 25 + tid % 7;
    inpA[(p >> 3) * 128 + e * 8 + (p & 7)] = (_Float16)0.f;
  }
  // geometry lane constants
  const int ge = tid >> 5, glane = tid & 31;
  const int gli = (glane < 25) ? glane : 0;
  const int gii = gli / 5, gjj = gli % 5;
  const float gdel = (gii == gjj) ? 1.f : 0.f;
  const int gbase = (l & 32) << 2;
  const int iA0 = gbase + gii * 20;
  const int iB0 = gbase + gjj * 4;
  const int iT0 = gbase + (gjj * 5 + gii) * 4;
  __syncthreads();

  // ---- SDE step loop: 5 barriers/step; sqrt = cheb4 + 3 NS, overlapped ----
  for (int st = 0; st < 5; st++) {
    float S = sig_s[ge * 28 + gli];
    float tr = 0.f;
#pragma unroll
    for (int d = 0; d < 5; d++) tr += bpf(gbase + 24 * d, S);
    const float That = S * (2.298851f / tr) - 1.068966f * gdel;
    float dwv[4] = {0.f, 0.f, 0.f, 0.f};
    if (w == 4) {
#pragma unroll
      for (int s = 0; s < 4; s++)
        dwv[s] = dWp[((rb + lq * 4 + s) * 5 + st) * 15 + oc];
    }
    float Yv, Zv;
    // p1: d0 || g0  (+ cheb4 preconditioner)
    mlp_pair<3>(inpA, F0[0], F0[1], b0s[0], b0s[1], role ? bufB : bufA, lm, lq, wbq * 32);
    {
      float T2 = mm5b(iA0, iB0, That, That);
      float X  = -1.13859f * That + 0.9901f * T2;
      float Zp = mm5b(iA0, iB0, T2, X)
               + 1.03702f * gdel - 0.21179f * That + 0.09756f * T2;
      Zv = Zp;
      float TZ = mm5b(iA0, iB0, That, Zp);
      Yv = 0.87f * TZ + 0.93f * Zp;
    }
    __syncthreads();
    // p2: d1 || g1  (+ NS1)
    mlp_pair<4>(role ? bufB : bufA, F1[0], F1[1], b1s[0], b1s[1],
                role ? bufD : bufC, lm, lq, wbq * 32);
    NS_ITER;
    __syncthreads();
    // p3: d2 || diff-head  (+ NS2)
    if (!role) {
      mlp_pair<4>(bufC, F2[0], F2[1], b2s[0], b2s[1], bufA, lm, lq, wbq * 32);
    } else if (w == 4) {
      f32x4 c = head4(bufD, Hf, lm, lq);
      if (lm < 15) {
#pragma unroll
        for (int s = 0; s < 4; s++) {
          float acc = c[s] + hb;
          float sp = (acc > 20.f) ? acc : __logf(1.f + __expf(acc));
          coeff2_s[(lq * 4 + s) * 16 + lm] = sp * dwv[s];
        }
      }
    }
    NS_ITER;
    __syncthreads();
    // p4: drift head  (+ NS3, finalize L)
    if (w == 0) {
      f32x4 c = head4(bufA, Hf, lm, lq);
      if (lm < 15) {
#pragma unroll
        for (int s = 0; s < 4; s++)
          coeff_s[(lq * 4 + s) * 16 + lm] = 0.2f * (c[s] + hb);
      }
    }
    NS_ITER;
    float L = Yv * sqrtf(0.5f * tr);
    __syncthreads();
    // p5: tangent build + expm (powers, deg-6) + exp-map + write
    {
      float av;
      if (gii == gjj) av = coeff_s[ge * 16 + gii] + coeff2_s[ge * 16 + gii];
      else {
        int p = gii < gjj ? gii : gjj, qq = gii < gjj ? gjj : gii;
        int i5 = 5 + (p * (9 - p)) / 2 + (qq - p - 1);
        av = (coeff_s[ge * 16 + i5] + coeff2_s[ge * 16 + i5]) * 0.70710678f;
      }
      float a2 = mm5b(iA0, iB0, av, av);
      float a3 = mm5b(iA0, iB0, a2, av);
      float q1 = gdel * 0.16666667f + av * 0.04166667f
               + a2 * 0.00833333f + a3 * 0.00138889f;
      float M = gdel + av + 0.5f * a2 + mm5b(iA0, iB0, a3, q1);
      float P2 = mm5b(iA0, iB0, L, M);
      float S2 = mm5b(iA0, iB0, P2, L);
      S2 = 0.5f * (S2 + bpf(iT0, S2));
      if (glane < 25) {
        sig_s[ge * 28 + gli] = S2;
        inpA[(gli >> 3) * 128 + ge * 8 + (gli & 7)] = (_Float16)S2;
      }
    }
    __syncthreads();
  }

  for (int idx = tid; idx < 400; idx += 512) {
    int e = idx / 25, k = idx % 25;
    outp[(rb + e) * 25 + k] = sig_s[e * 28 + k];
  }
}

extern "C" void kernel_launch(void* const* d_in, const int* in_sizes, int n_in,
                              void* d_out, int out_size, void* d_ws, size_t ws_size,
                              hipStream_t stream) {
  const float* ctp = (const float*)d_in[0];
  const float* dWp = (const float*)d_in[1];
  const float* wih = (const float*)d_in[2];
  const float* whh = (const float*)d_in[3];
  const float* gb  = (const float*)d_in[4];
  const float* gbn = (const float*)d_in[5];
  const float* pw  = (const float*)d_in[6];
  const float* pb  = (const float*)d_in[7];
  const float* dw0 = (const float*)d_in[8];
  const float* db0 = (const float*)d_in[9];
  const float* dw1 = (const float*)d_in[10];
  const float* db1 = (const float*)d_in[11];
  const float* dw2 = (const float*)d_in[12];
  const float* db2 = (const float*)d_in[13];
  const float* dw3 = (const float*)d_in[14];
  const float* db3 = (const float*)d_in[15];
  const float* gw0 = (const float*)d_in[16];
  const float* gb0 = (const float*)d_in[17];
  const float* gw1 = (const float*)d_in[18];
  const float* gb1 = (const float*)d_in[19];
  const float* gw2 = (const float*)d_in[20];
  const float* gb2 = (const float*)d_in[21];
  uint* wsu = (uint*)d_ws;

  hipLaunchKernelGGL(prep_kernel, dim3(288), dim3(256), 0, stream,
                     wih, whh, pw, dw0, dw1, dw2, gw0, gw1, dw3, gw2, wsu);
  hipLaunchKernelGGL(fused_kernel, dim3(256), dim3(512), 0, stream,
                     ctp, dWp, wsu, gb, gbn, pb,
                     db0, db1, db2, db3, gb0, gb1, gb2, (float*)d_out);
}

// Round 12
// 161.727 us; speedup vs baseline: 1.2367x; 1.0247x over previous
//
#include <hip/hip_runtime.h>
#include <hip/hip_bf16.h>

typedef unsigned int uint;

#define T_STEPS 32

// ---- workspace dword offsets ----
#define OFF_WB    0        // 30720: GRU B-frags
#define OFF_PJB   30720    // 4096 : proj B-frags (waves 0-3)
#define OFF_D0B   34816    // 6144 : drift_w0 B-frags (8 slots x 3 kt)
#define OFF_D1B   40960    // 8192
#define OFF_D2B   49152    // 8192
#define OFF_G0B   57344    // 6144
#define OFF_G1B   63488    // 8192
#define OFF_W3B   71680    // 1024 : drift_w3 head (N pad 15->16)
#define OFF_G2B   72704    // 1024 : diff_w2 head

typedef _Float16 half8 __attribute__((ext_vector_type(8)));
typedef float    f32x4 __attribute__((ext_vector_type(4)));

union FB { uint4 u4; half8 h; };

__device__ inline uint pack2f(float a, float b) {
  _Float16 ha = (_Float16)a, hb = (_Float16)b;
  unsigned short ua, ub;
  __builtin_memcpy(&ua, &ha, 2);
  __builtin_memcpy(&ub, &hb, 2);
  return (uint)ua | ((uint)ub << 16);
}

// ---- fast activations: Pade(3/2) tanh + clamp, raw v_rcp ----
__device__ inline float rcpf(float x) {
#if __has_builtin(__builtin_amdgcn_rcpf)
  return __builtin_amdgcn_rcpf(x);
#else
  return 1.f / x;
#endif
}
__device__ inline float tanh_fast(float x) {
  float t = x * x;
  float num = x * (27.f + t);
  float den = fmaf(t, 9.f, 27.f);
  float r = num * rcpf(den);
  return fminf(1.f, fmaxf(-1.f, r));
}
__device__ inline float sigm(float x) { return fmaf(tanh_fast(0.5f * x), 0.5f, 0.5f); }
__device__ inline float silu_f(float x) { return x * sigm(x); }

__device__ inline float map89(const float* __restrict__ W, int u, int k) {
  if (k < 25) return W[u * 89 + k];
  if (k < 32) return 0.f;
  return W[u * 89 + k - 7];   // ctx part: 25 + (k-32)
}

// ======================= weight pre-pack =======================
__global__ __launch_bounds__(256) void prep_kernel(
    const float* __restrict__ wih, const float* __restrict__ whh,
    const float* __restrict__ pw,
    const float* __restrict__ dw0, const float* __restrict__ dw1,
    const float* __restrict__ dw2, const float* __restrict__ gw0,
    const float* __restrict__ gw1, const float* __restrict__ dw3,
    const float* __restrict__ gw2, uint* __restrict__ wsu) {
  int id = blockIdx.x * 256 + threadIdx.x;
  if (id < 30720) {
    int i = id & 3, l = (id >> 2) & 63, t3 = id >> 8;
    int kt = t3 % 5, wg = t3 / 5;
    int w = wg / 3, gi = wg % 3;
    int row = gi * 128 + w * 16 + (l & 15);
    int k = ((l >> 4) << 3) + i * 2;
    float a, b;
    if (kt == 0) {
      a = (k     < 25) ? wih[row * 25 + k]     : 0.f;
      b = (k + 1 < 25) ? wih[row * 25 + k + 1] : 0.f;
    } else {
      int kh = (kt - 1) * 32 + k;
      a = whh[row * 128 + kh];
      b = whh[row * 128 + kh + 1];
    }
    wsu[OFF_WB + id] = pack2f(a, b);
  } else if (id < 34816) {               // proj B-frags: (w*4+kt)
    int t = id - 30720;
    int i = t & 3, l = (t >> 2) & 63, wkt = t >> 8;
    int kt = wkt & 3, w = wkt >> 2;
    int u = w * 16 + (l & 15);
    int k = kt * 32 + ((l >> 4) << 3) + i * 2;
    wsu[OFF_PJB + t] = pack2f(pw[u * 128 + k], pw[u * 128 + k + 1]);
  } else if (id < 40960) {               // drift_w0 (89-in, 8 slots x 3 kt)
    int t = id - 34816;
    int i = t & 3, l = (t >> 2) & 63, wkt = t >> 8;
    int kt = wkt % 3, w = wkt / 3;
    int u = w * 16 + (l & 15);
    int k = kt * 32 + ((l >> 4) << 3) + i * 2;
    wsu[OFF_D0B + t] = pack2f(map89(dw0, u, k), map89(dw0, u, k + 1));
  } else if (id < 49152) {               // drift_w1
    int t = id - 40960;
    int i = t & 3, l = (t >> 2) & 63, wkt = t >> 8;
    int kt = wkt & 3, w = wkt >> 2;
    int u = w * 16 + (l & 15);
    int k = kt * 32 + ((l >> 4) << 3) + i * 2;
    wsu[OFF_D1B + t] = pack2f(dw1[u * 128 + k], dw1[u * 128 + k + 1]);
  } else if (id < 57344) {               // drift_w2
    int t = id - 49152;
    int i = t & 3, l = (t >> 2) & 63, wkt = t >> 8;
    int kt = wkt & 3, w = wkt >> 2;
    int u = w * 16 + (l & 15);
    int k = kt * 32 + ((l >> 4) << 3) + i * 2;
    wsu[OFF_D2B + t] = pack2f(dw2[u * 128 + k], dw2[u * 128 + k + 1]);
  } else if (id < 63488) {               // diff_w0 (89-in)
    int t = id - 57344;
    int i = t & 3, l = (t >> 2) & 63, wkt = t >> 8;
    int kt = wkt % 3, w = wkt / 3;
    int u = w * 16 + (l & 15);
    int k = kt * 32 + ((l >> 4) << 3) + i * 2;
    wsu[OFF_G0B + t] = pack2f(map89(gw0, u, k), map89(gw0, u, k + 1));
  } else if (id < 71680) {               // diff_w1
    int t = id - 63488;
    int i = t & 3, l = (t >> 2) & 63, wkt = t >> 8;
    int kt = wkt & 3, w = wkt >> 2;
    int u = w * 16 + (l & 15);
    int k = kt * 32 + ((l >> 4) << 3) + i * 2;
    wsu[OFF_G1B + t] = pack2f(gw1[u * 128 + k], gw1[u * 128 + k + 1]);
  } else if (id < 72704) {               // drift_w3 head (15 outs, pad 16)
    int t = id - 71680;
    int i = t & 3, l = (t >> 2) & 63, kt = t >> 8;
    int o = l & 15;
    int k = kt * 32 + ((l >> 4) << 3) + i * 2;
    float a = (o < 15) ? dw3[o * 128 + k]     : 0.f;
    float b = (o < 15) ? dw3[o * 128 + k + 1] : 0.f;
    wsu[OFF_W3B + t] = pack2f(a, b);
  } else if (id < 73728) {               // diff_w2 head
    int t = id - 72704;
    int i = t & 3, l = (t >> 2) & 63, kt = t >> 8;
    int o = l & 15;
    int k = kt * 32 + ((l >> 4) << 3) + i * 2;
    float a = (o < 15) ? gw2[o * 128 + k]     : 0.f;
    float b = (o < 15) ? gw2[o * 128 + k + 1] : 0.f;
    wsu[OFF_G2B + t] = pack2f(a, b);
  }
}

// MLP dual-slot phase: A-frags in LDS, B-frags in VGPRs.
template <int KT>
__device__ inline void mlp_pair(const _Float16* __restrict__ aA,
                                const FB* B0, const FB* B1,
                                float bias0, float bias1,
                                _Float16* __restrict__ outA,
                                int lm, int lq, int ubase) {
  f32x4 c0 = {0.f, 0.f, 0.f, 0.f}, c1 = {0.f, 0.f, 0.f, 0.f};
#pragma unroll
  for (int kt = 0; kt < KT; kt++) {
    half8 a = *(const half8*)(aA + ((kt * 4 + lq) * 16 + lm) * 8);
    c0 = __builtin_amdgcn_mfma_f32_16x16x32_f16(a, B0[kt].h, c0, 0, 0, 0);
    c1 = __builtin_amdgcn_mfma_f32_16x16x32_f16(a, B1[kt].h, c1, 0, 0, 0);
  }
  int u0 = ubase + lm, u1 = ubase + 16 + lm;
  int base0 = (u0 >> 3) * 128 + (u0 & 7);
  int base1 = (u1 >> 3) * 128 + (u1 & 7);
#pragma unroll
  for (int s = 0; s < 4; s++) {
    outA[base0 + (lq * 4 + s) * 8] = (_Float16)silu_f(c0[s] + bias0);
    outA[base1 + (lq * 4 + s) * 8] = (_Float16)silu_f(c1[s] + bias1);
  }
}

// Layer-0 with step-invariant ctx contribution pre-accumulated (C-operand).
__device__ inline void mlp_pair_pre(const _Float16* __restrict__ aA,
                                    const FB& B0k0, const FB& B1k0,
                                    f32x4 cc0, f32x4 cc1,
                                    float bias0, float bias1,
                                    _Float16* __restrict__ outA,
                                    int lm, int lq, int ubase) {
  half8 a = *(const half8*)(aA + ((0 * 4 + lq) * 16 + lm) * 8);  // sigma ktile
  f32x4 c0 = __builtin_amdgcn_mfma_f32_16x16x32_f16(a, B0k0.h, cc0, 0, 0, 0);
  f32x4 c1 = __builtin_amdgcn_mfma_f32_16x16x32_f16(a, B1k0.h, cc1, 0, 0, 0);
  int u0 = ubase + lm, u1 = ubase + 16 + lm;
  int base0 = (u0 >> 3) * 128 + (u0 & 7);
  int base1 = (u1 >> 3) * 128 + (u1 & 7);
#pragma unroll
  for (int s = 0; s < 4; s++) {
    outA[base0 + (lq * 4 + s) * 8] = (_Float16)silu_f(c0[s] + bias0);
    outA[base1 + (lq * 4 + s) * 8] = (_Float16)silu_f(c1[s] + bias1);
  }
}

__device__ inline f32x4 head4(const _Float16* __restrict__ aA, const FB* H,
                              int lm, int lq) {
  f32x4 c = {0.f, 0.f, 0.f, 0.f};
#pragma unroll
  for (int kt = 0; kt < 4; kt++) {
    half8 a = *(const half8*)(aA + ((kt * 4 + lq) * 16 + lm) * 8);
    c = __builtin_amdgcn_mfma_f32_16x16x32_f16(a, H[kt].h, c, 0, 0, 0);
  }
  return c;
}

// ---- 5x5 wave-parallel matmul via raw ds_bpermute (hoisted addresses) ----
__device__ inline float bpf(int addr, float v) {
  return __int_as_float(__builtin_amdgcn_ds_bpermute(addr, __float_as_int(v)));
}
__device__ inline float mm5b(int iA, int iB, float A, float B) {
  float c = 0.f;
#pragma unroll
  for (int k = 0; k < 5; k++)
    c = fmaf(bpf(iA + 4 * k, A), bpf(iB + 20 * k, B), c);
  return c;
}

#define NS_ITER do { \
  float P_  = mm5b(iA0, iB0, Zv, Yv); \
  float Tm_ = 1.5f * gdel - 0.5f * P_; \
  float Yn_ = mm5b(iA0, iB0, Yv, Tm_); \
  float Zn_ = mm5b(iA0, iB0, Tm_, Zv); \
  Yv = Yn_; Zv = Zn_; } while (0)

// ======================= fused GRU + SDE =======================
// grid 256 x 512; block owns 16 batch rows.
__global__ __launch_bounds__(512) void fused_kernel(
    const float* __restrict__ ctp, const float* __restrict__ dWp,
    const uint* __restrict__ wsu,
    const float* __restrict__ gbias, const float* __restrict__ gbn,
    const float* __restrict__ projb,
    const float* __restrict__ db0, const float* __restrict__ db1,
    const float* __restrict__ db2, const float* __restrict__ b3,
    const float* __restrict__ gb0, const float* __restrict__ gb1,
    const float* __restrict__ gb2, float* __restrict__ outp) {
  __shared__ __align__(16) _Float16 bigbuf[16384];           // 32KB: x2 / SDE bufs
  __shared__ __align__(16) _Float16 hf[2][4][4][16][8];      // 8KB dbuf h A-frags
  __shared__ float sig_s[16 * 28];
  __shared__ float coeff_s[256];
  __shared__ float coeff2_s[256];
  const int tid = threadIdx.x;
  const int rb = blockIdx.x * 16;
  uint* bigu = (uint*)bigbuf;

  // ---- stage symmetrized features as A-frags (x2 = bigbuf) ----
  for (int idx = tid; idx < T_STEPS * 16 * 16; idx += 512) {
    int k2 = idx & 15, r = (idx >> 4) & 15, t = idx >> 8;
    const float* base = ctp + ((rb + r) * T_STEPS + t) * 25;
    int k0 = 2 * k2;
    float v0 = 0.f, v1 = 0.f;
    if (k0 < 25)     { int i5 = k0 / 5,     j5 = k0 % 5;     v0 = 0.5f * (base[i5*5+j5] + base[j5*5+i5]); }
    if (k0 + 1 < 25) { int i5 = (k0+1) / 5, j5 = (k0+1) % 5; v1 = 0.5f * (base[i5*5+j5] + base[j5*5+i5]); }
    int q = k2 >> 2, jh = k2 & 3;
    bigu[((t * 4 + q) * 16 + r) * 4 + jh] = pack2f(v0, v1);
  }

  const int w = tid >> 6, l = tid & 63;
  const int lm = l & 15, lq = l >> 4;
  const int u = w * 16 + lm;
  const int ku = u >> 5, qu = (u >> 3) & 3, ju = u & 7;
  FB Bf[3][5];
  const uint4* wb4p = (const uint4*)(wsu + OFF_WB);
#pragma unroll
  for (int gi = 0; gi < 3; gi++)
#pragma unroll
    for (int kt = 0; kt < 5; kt++)
      Bf[gi][kt].u4 = wb4p[((w * 3 + gi) * 5 + kt) * 64 + l];
  const float br = gbias[u], bz = gbias[128 + u], bg = gbias[256 + u], bn = gbn[u];
  float hprev[4] = {0.f, 0.f, 0.f, 0.f};
  __syncthreads();

  // ---- GRU t-loop (1 barrier/step, x-part software-pipelined) ----
  f32x4 z4 = {0.f, 0.f, 0.f, 0.f};
  half8 axn = *(const half8*)(bigbuf + ((0 * 4 + lq) * 16 + lm) * 8);
  f32x4 pxr = __builtin_amdgcn_mfma_f32_16x16x32_f16(axn, Bf[0][0].h, z4, 0, 0, 0);
  f32x4 pxz = __builtin_amdgcn_mfma_f32_16x16x32_f16(axn, Bf[1][0].h, z4, 0, 0, 0);
  f32x4 pxg = __builtin_amdgcn_mfma_f32_16x16x32_f16(axn, Bf[2][0].h, z4, 0, 0, 0);
  for (int t = 0; t < T_STEPS; t++) {
    f32x4 cr = pxr, cz = pxz, cgv = pxg;
    f32x4 ch = {0.f, 0.f, 0.f, 0.f};
    if (t > 0) {
      const int p = t & 1;
#pragma unroll
      for (int kk = 0; kk < 4; kk++) {
        half8 ah = *(const half8*)(&hf[p][kk][lq][lm][0]);
        cr = __builtin_amdgcn_mfma_f32_16x16x32_f16(ah, Bf[0][1 + kk].h, cr, 0, 0, 0);
        cz = __builtin_amdgcn_mfma_f32_16x16x32_f16(ah, Bf[1][1 + kk].h, cz, 0, 0, 0);
        ch = __builtin_amdgcn_mfma_f32_16x16x32_f16(ah, Bf[2][1 + kk].h, ch, 0, 0, 0);
      }
    }
    if (t < T_STEPS - 1) {   // prefetch next step's x-part (independent of h)
      axn = *(const half8*)(bigbuf + (((t + 1) * 4 + lq) * 16 + lm) * 8);
      pxr = __builtin_amdgcn_mfma_f32_16x16x32_f16(axn, Bf[0][0].h, z4, 0, 0, 0);
      pxz = __builtin_amdgcn_mfma_f32_16x16x32_f16(axn, Bf[1][0].h, z4, 0, 0, 0);
      pxg = __builtin_amdgcn_mfma_f32_16x16x32_f16(axn, Bf[2][0].h, z4, 0, 0, 0);
    }
    const int wp = (t + 1) & 1;
#pragma unroll
    for (int s = 0; s < 4; s++) {
      float r = sigm(cr[s] + br);
      float z = sigm(cz[s] + bz);
      float g = tanh_fast(cgv[s] + bg + r * (ch[s] + bn));
      float hn = (1.f - z) * g + z * hprev[s];
      hprev[s] = hn;
      hf[wp][ku][qu][lq * 4 + s][ju] = (_Float16)hn;
    }
    __syncthreads();
  }

  // ---- SDE B-frag preload (registers), role-split ----
  const int role = w >> 2;                 // 0: drift (waves 0-3), 1: diff (4-7)
  const int wbq = w & 3;
  FB F0[2][3], F1[2][4], F2[2][4], Pf[4], Hf[4];
  {
    const uint4* p0 = (const uint4*)(wsu + (role ? OFF_G0B : OFF_D0B));
    const uint4* p1 = (const uint4*)(wsu + (role ? OFF_G1B : OFF_D1B));
    const uint4* p2 = (const uint4*)(wsu + (role ? OFF_G1B : OFF_D2B)); // diff: dummy
#pragma unroll
    for (int s = 0; s < 2; s++) {
      int slot = wbq * 2 + s;
#pragma unroll
      for (int kt = 0; kt < 3; kt++) F0[s][kt].u4 = p0[(slot * 3 + kt) * 64 + l];
#pragma unroll
      for (int kt = 0; kt < 4; kt++) {
        F1[s][kt].u4 = p1[(slot * 4 + kt) * 64 + l];
        F2[s][kt].u4 = p2[(slot * 4 + kt) * 64 + l];
      }
    }
  }
  if (w < 4) {
#pragma unroll
    for (int kt = 0; kt < 4; kt++)
      Pf[kt].u4 = ((const uint4*)(wsu + OFF_PJB))[(w * 4 + kt) * 64 + l];
  }
  if (w == 0) {
#pragma unroll
    for (int kt = 0; kt < 4; kt++)
      Hf[kt].u4 = ((const uint4*)(wsu + OFF_W3B))[kt * 64 + l];
  } else if (w == 4) {
#pragma unroll
    for (int kt = 0; kt < 4; kt++)
      Hf[kt].u4 = ((const uint4*)(wsu + OFF_G2B))[kt * 64 + l];
  }
  float b0s[2], b1s[2], b2s[2];
#pragma unroll
  for (int s = 0; s < 2; s++) {
    int us = wbq * 32 + s * 16 + lm;
    b0s[s] = role ? gb0[us] : db0[us];
    b1s[s] = role ? gb1[us] : db1[us];
    b2s[s] = role ? 0.f : db2[us];
  }
  const int oc = (lm < 15) ? lm : 0;
  const float hb = (w == 0) ? b3[oc] : ((w == 4) ? gb2[oc] : 0.f);

  _Float16* inpA = bigbuf;          // 3 ktiles (k: 0-24 sigma | pad | 32-95 ctx)
  _Float16* bufA = bigbuf + 1536;   // drift d0 out / d2 out
  _Float16* bufB = bigbuf + 3584;   // diff g0 out
  _Float16* bufC = bigbuf + 5632;   // drift d1 out
  _Float16* bufD = bigbuf + 7680;   // diff g1 out

  // proj via MFMA (waves 0-3): ctx -> inpA ctx part
  if (w < 4) {
    f32x4 c = {0.f, 0.f, 0.f, 0.f};
#pragma unroll
    for (int kt = 0; kt < 4; kt++) {
      half8 a = *(const half8*)(&hf[0][kt][lq][lm][0]);
      c = __builtin_amdgcn_mfma_f32_16x16x32_f16(a, Pf[kt].h, c, 0, 0, 0);
    }
    const float pbv = projb[u];
    int kk = 32 + u, base = (kk >> 3) * 128 + (kk & 7);
#pragma unroll
    for (int s = 0; s < 4; s++)
      inpA[base + (lq * 4 + s) * 8] = (_Float16)(c[s] + pbv);
  }
  // sigma init + pad
  for (int idx = tid; idx < 400; idx += 512) {
    int e = idx / 25, k = idx % 25;
    int i5 = k / 5, j5 = k % 5;
    const float* base = ctp + ((rb + e) * T_STEPS + 31) * 25;
    float v = 0.5f * (base[i5 * 5 + j5] + base[j5 * 5 + i5]);
    sig_s[e * 28 + k] = v;
    inpA[(k >> 3) * 128 + e * 8 + (k & 7)] = (_Float16)v;
  }
  if (tid < 112) {
    int e = tid / 7, p = 25 + tid % 7;
    inpA[(p >> 3) * 128 + e * 8 + (p & 7)] = (_Float16)0.f;
  }
  // geometry lane constants
  const int ge = tid >> 5, glane = tid & 31;
  const int gli = (glane < 25) ? glane : 0;
  const int gii = gli / 5, gjj = gli % 5;
  const float gdel = (gii == gjj) ? 1.f : 0.f;
  const int gbase = (l & 32) << 2;
  const int iA0 = gbase + gii * 20;
  const int iB0 = gbase + gjj * 4;
  const int iT0 = gbase + (gjj * 5 + gii) * 4;
  __syncthreads();

  // step-invariant ctx contribution to layer0 (ktiles 1-2), both slots
  f32x4 cc0 = {0.f, 0.f, 0.f, 0.f}, cc1 = {0.f, 0.f, 0.f, 0.f};
#pragma unroll
  for (int kt = 1; kt < 3; kt++) {
    half8 a = *(const half8*)(inpA + ((kt * 4 + lq) * 16 + lm) * 8);
    cc0 = __builtin_amdgcn_mfma_f32_16x16x32_f16(a, F0[0][kt].h, cc0, 0, 0, 0);
    cc1 = __builtin_amdgcn_mfma_f32_16x16x32_f16(a, F0[1][kt].h, cc1, 0, 0, 0);
  }

  // ---- SDE step loop: 5 barriers/step; sqrt = cheb4 + NS1 + NS2 ----
  for (int st = 0; st < 5; st++) {
    float S = sig_s[ge * 28 + gli];
    float tr = 0.f;
#pragma unroll
    for (int d = 0; d < 5; d++) tr += bpf(gbase + 24 * d, S);
    const float That = S * (2.298851f / tr) - 1.068966f * gdel;
    float dwv[4] = {0.f, 0.f, 0.f, 0.f};
    if (w == 4) {
#pragma unroll
      for (int s = 0; s < 4; s++)
        dwv[s] = dWp[((rb + lq * 4 + s) * 5 + st) * 15 + oc];
    }
    float Yv, Zv;
    // p1: d0 || g0 (sigma ktile only; ctx pre-accumulated) + cheb4
    mlp_pair_pre(inpA, F0[0][0], F0[1][0], cc0, cc1, b0s[0], b0s[1],
                 role ? bufB : bufA, lm, lq, wbq * 32);
    {
      float T2 = mm5b(iA0, iB0, That, That);
      float X  = -1.13859f * That + 0.9901f * T2;
      float Zp = mm5b(iA0, iB0, T2, X)
               + 1.03702f * gdel - 0.21179f * That + 0.09756f * T2;
      Zv = Zp;
      float TZ = mm5b(iA0, iB0, That, Zp);
      Yv = 0.87f * TZ + 0.93f * Zp;
    }
    __syncthreads();
    // p2: d1 || g1  (+ NS1)
    mlp_pair<4>(role ? bufB : bufA, F1[0], F1[1], b1s[0], b1s[1],
                role ? bufD : bufC, lm, lq, wbq * 32);
    NS_ITER;
    __syncthreads();
    // p3: d2 || diff-head  (+ NS2)
    if (!role) {
      mlp_pair<4>(bufC, F2[0], F2[1], b2s[0], b2s[1], bufA, lm, lq, wbq * 32);
    } else if (w == 4) {
      f32x4 c = head4(bufD, Hf, lm, lq);
      if (lm < 15) {
#pragma unroll
        for (int s = 0; s < 4; s++) {
          float acc = c[s] + hb;
          float sp = (acc > 20.f) ? acc : __logf(1.f + __expf(acc));
          coeff2_s[(lq * 4 + s) * 16 + lm] = sp * dwv[s];
        }
      }
    }
    NS_ITER;
    __syncthreads();
    // p4: drift head; finalize L
    if (w == 0) {
      f32x4 c = head4(bufA, Hf, lm, lq);
      if (lm < 15) {
#pragma unroll
        for (int s = 0; s < 4; s++)
          coeff_s[(lq * 4 + s) * 16 + lm] = 0.2f * (c[s] + hb);
      }
    }
    float L = Yv * sqrtf(0.5f * tr);
    __syncthreads();
    // p5: tangent build + expm (powers, deg-6) + exp-map + write
    {
      float av;
      if (gii == gjj) av = coeff_s[ge * 16 + gii] + coeff2_s[ge * 16 + gii];
      else {
        int p = gii < gjj ? gii : gjj, qq = gii < gjj ? gjj : gii;
        int i5 = 5 + (p * (9 - p)) / 2 + (qq - p - 1);
        av = (coeff_s[ge * 16 + i5] + coeff2_s[ge * 16 + i5]) * 0.70710678f;
      }
      float a2 = mm5b(iA0, iB0, av, av);
      float a3 = mm5b(iA0, iB0, a2, av);
      float q1 = gdel * 0.16666667f + av * 0.04166667f
               + a2 * 0.00833333f + a3 * 0.00138889f;
      float M = gdel + av + 0.5f * a2 + mm5b(iA0, iB0, a3, q1);
      float P2 = mm5b(iA0, iB0, L, M);
      float S2 = mm5b(iA0, iB0, P2, L);
      S2 = 0.5f * (S2 + bpf(iT0, S2));
      if (glane < 25) {
        sig_s[ge * 28 + gli] = S2;
        inpA[(gli >> 3) * 128 + ge * 8 + (gli & 7)] = (_Float16)S2;
      }
    }
    __syncthreads();
  }

  for (int idx = tid; idx < 400; idx += 512) {
    int e = idx / 25, k = idx % 25;
    outp[(rb + e) * 25 + k] = sig_s[e * 28 + k];
  }
}

extern "C" void kernel_launch(void* const* d_in, const int* in_sizes, int n_in,
                              void* d_out, int out_size, void* d_ws, size_t ws_size,
                              hipStream_t stream) {
  const float* ctp = (const float*)d_in[0];
  const float* dWp = (const float*)d_in[1];
  const float* wih = (const float*)d_in[2];
  const float* whh = (const float*)d_in[3];
  const float* gb  = (const float*)d_in[4];
  const float* gbn = (const float*)d_in[5];
  const float* pw  = (const float*)d_in[6];
  const float* pb  = (const float*)d_in[7];
  const float* dw0 = (const float*)d_in[8];
  const float* db0 = (const float*)d_in[9];
  const float* dw1 = (const float*)d_in[10];
  const float* db1 = (const float*)d_in[11];
  const float* dw2 = (const float*)d_in[12];
  const float* db2 = (const float*)d_in[13];
  const float* dw3 = (const float*)d_in[14];
  const float* db3 = (const float*)d_in[15];
  const float* gw0 = (const float*)d_in[16];
  const float* gb0 = (const float*)d_in[17];
  const float* gw1 = (const float*)d_in[18];
  const float* gb1 = (const float*)d_in[19];
  const float* gw2 = (const float*)d_in[20];
  const float* gb2 = (const float*)d_in[21];
  uint* wsu = (uint*)d_ws;

  hipLaunchKernelGGL(prep_kernel, dim3(288), dim3(256), 0, stream,
                     wih, whh, pw, dw0, dw1, dw2, gw0, gw1, dw3, gw2, wsu);
  hipLaunchKernelGGL(fused_kernel, dim3(256), dim3(512), 0, stream,
                     ctp, dWp, wsu, gb, gbn, pb,
                     db0, db1, db2, db3, gb0, gb1, gb2, (float*)d_out);
}